// Round 3
// baseline (961.455 us; speedup 1.0000x reference)
//
#include <hip/hip_runtime.h>
#include <hip/hip_bf16.h>
#include <math.h>

// Problem constants
#define BB 8
#define LL 1024
#define DD 1024
#define FF 4096
#define NHH 8
#define HSS 128
#define SCALE 0.08838834764831845f  // 1/sqrt(128)

typedef __bf16 bf16;
typedef __bf16 bf16x8 __attribute__((ext_vector_type(8)));
typedef float f32x4 __attribute__((ext_vector_type(4)));

__device__ inline void async_copy16(const void* g, void* l) {
  __builtin_amdgcn_global_load_lds(
      (const __attribute__((address_space(1))) unsigned int*)g,
      (__attribute__((address_space(3))) unsigned int*)l, 16, 0, 0);
}

// ---------------------------------------------------------------------------
// Transpose + cast: W [K][N] fp32 -> Wt [N][K] bf16
// ---------------------------------------------------------------------------
__global__ __launch_bounds__(256)
void transpose_cast_kernel(const float* __restrict__ W, bf16* __restrict__ Wt,
                           int K, int N) {
  __shared__ float tile[32][33];
  int n0 = blockIdx.x * 32, k0 = blockIdx.y * 32;
  int tx = threadIdx.x, ty = threadIdx.y;
#pragma unroll
  for (int i = 0; i < 32; i += 8)
    tile[ty + i][tx] = W[(size_t)(k0 + ty + i) * N + n0 + tx];
  __syncthreads();
#pragma unroll
  for (int i = 0; i < 32; i += 8)
    Wt[(size_t)(n0 + ty + i) * K + k0 + tx] = (bf16)tile[tx][ty + i];
}

__global__ __launch_bounds__(256)
void cast_bf16_kernel(const float* __restrict__ src, bf16* __restrict__ dst, int n) {
  int i = blockIdx.x * blockDim.x + threadIdx.x;
  if (i < n) dst[i] = (bf16)src[i];
}

// ---------------------------------------------------------------------------
// LayerNorm: x [8192][1024] fp32 -> out bf16
// ---------------------------------------------------------------------------
__global__ __launch_bounds__(256)
void ln_kernel(const float* __restrict__ x, const float* __restrict__ g,
               const float* __restrict__ bta, bf16* __restrict__ out) {
  int row = blockIdx.x;
  int tid = threadIdx.x;
  const float4 v = ((const float4*)(x + (size_t)row * DD))[tid];
  float s = v.x + v.y + v.z + v.w;
  float s2 = v.x * v.x + v.y * v.y + v.z * v.z + v.w * v.w;
#pragma unroll
  for (int o = 32; o > 0; o >>= 1) {
    s += __shfl_down(s, o);
    s2 += __shfl_down(s2, o);
  }
  __shared__ float a1[4], a2[4];
  int wave = tid >> 6;
  if ((tid & 63) == 0) { a1[wave] = s; a2[wave] = s2; }
  __syncthreads();
  s = a1[0] + a1[1] + a1[2] + a1[3];
  s2 = a2[0] + a2[1] + a2[2] + a2[3];
  float mu = s * (1.0f / DD);
  float rstd = rsqrtf(s2 * (1.0f / DD) - mu * mu + 1e-5f);
  float4 gv = ((const float4*)g)[tid];
  float4 bv = ((const float4*)bta)[tid];
  bf16* o4 = out + (size_t)row * DD + tid * 4;
  o4[0] = (bf16)((v.x - mu) * rstd * gv.x + bv.x);
  o4[1] = (bf16)((v.y - mu) * rstd * gv.y + bv.y);
  o4[2] = (bf16)((v.z - mu) * rstd * gv.z + bv.z);
  o4[3] = (bf16)((v.w - mu) * rstd * gv.w + bv.w);
}

// ---------------------------------------------------------------------------
// GEMM: C[M][N] = A[M][K](bf16) * Bt[N][K](bf16)^T + bias
// EPI 0: -> bf16   EPI 1: gelu -> bf16   EPI 2: + res(fp32) -> fp32
// 128x128 tile, BK=32, 4 waves each 64x64 via 4x4 mfma_16x16x32_bf16
// ---------------------------------------------------------------------------
template <int EPI>
__global__ __launch_bounds__(256)
void gemm_kernel(const bf16* __restrict__ A, const bf16* __restrict__ Bt,
                 const float* __restrict__ bias, const float* __restrict__ res,
                 void* __restrict__ Cout, int M, int N, int K) {
  __shared__ bf16 Als[128 * 32];
  __shared__ bf16 Bls[128 * 32];
  int tid = threadIdx.x;
  int wave = tid >> 6, lane = tid & 63;
  int l15 = lane & 15, quad = lane >> 4;
  int m0 = blockIdx.y * 128, n0 = blockIdx.x * 128;
  int wm = (wave >> 1) * 64, wn = (wave & 1) * 64;
  f32x4 acc[4][4] = {};

  for (int k0 = 0; k0 < K; k0 += 32) {
    __syncthreads();
#pragma unroll
    for (int i = 0; i < 2; i++) {
      int t = i * 256 + tid;
      int row = t >> 2, kc = (t & 3) << 3;
      async_copy16(A + (size_t)(m0 + row) * K + k0 + kc, &Als[t * 8]);
      async_copy16(Bt + (size_t)(n0 + row) * K + k0 + kc, &Bls[t * 8]);
    }
    __syncthreads();
    bf16x8 af[4], bfr[4];
#pragma unroll
    for (int mt = 0; mt < 4; mt++)
      af[mt] = *(const bf16x8*)&Als[(wm + mt * 16 + l15) * 32 + quad * 8];
#pragma unroll
    for (int nt = 0; nt < 4; nt++)
      bfr[nt] = *(const bf16x8*)&Bls[(wn + nt * 16 + l15) * 32 + quad * 8];
#pragma unroll
    for (int mt = 0; mt < 4; mt++)
#pragma unroll
      for (int nt = 0; nt < 4; nt++)
        acc[mt][nt] = __builtin_amdgcn_mfma_f32_16x16x32_bf16(af[mt], bfr[nt],
                                                              acc[mt][nt], 0, 0, 0);
  }

#pragma unroll
  for (int mt = 0; mt < 4; mt++) {
#pragma unroll
    for (int nt = 0; nt < 4; nt++) {
      int col = n0 + wn + nt * 16 + l15;
      float bv = bias[col];
#pragma unroll
      for (int r = 0; r < 4; r++) {
        int row = m0 + wm + mt * 16 + quad * 4 + r;
        float v = acc[mt][nt][r] + bv;
        if (EPI == 1) v = 0.5f * v * (1.0f + erff(v * 0.7071067811865475f));
        if (EPI == 2) {
          v += res[(size_t)row * N + col];
          ((float*)Cout)[(size_t)row * N + col] = v;
        } else {
          ((bf16*)Cout)[(size_t)row * N + col] = (bf16)v;
        }
      }
    }
  }
}

// ---------------------------------------------------------------------------
// Flash attention v3 with relative-position skew bias.
// scores[q,k] = (q.k + q.Er[1023-q+k]) * scale, causal.
// Block: 256 thr (4 waves), each wave owns 16 q rows; BQ=64, BK=64.
// v3 = v2 (swizzled Vls, no Rls, 2 barriers/tile, reg prefetch, __expf, LPT)
//      minus the spill source: no min-waves clause, sv[] folded into sa[].
// ---------------------------------------------------------------------------
__global__ __launch_bounds__(256)
void flash_kernel(const bf16* __restrict__ qkv, const bf16* __restrict__ Erb,
                  bf16* __restrict__ y) {
  __shared__ bf16 Kls[64][136];    // K tile [kk][d], rows padded to 272B
  __shared__ bf16 Vls[128][72];    // V^T [d][kk] with octet rotation swizzle
  __shared__ bf16 Pls[4][16][72];  // per-wave P tile (A-frag layout)

  int tid = threadIdx.x, wave = tid >> 6, lane = tid & 63;
  int l15 = lane & 15, quad = lane >> 4;
  int qb = 15 - blockIdx.x;  // LPT: heavy q-tiles dispatch first
  int h = blockIdx.y, b = blockIdx.z;
  int qw0 = qb * 64 + wave * 16;

  const size_t rs = 3 * DD;
  const bf16* qbase = qkv + (size_t)b * LL * rs + h * HSS;
  const bf16* kbase = qbase + DD;
  const bf16* vbase = qbase + 2 * DD;

  // Q fragments (A-operand), row = qw0+l15, contraction d split 4x32
  bf16x8 qf[4];
#pragma unroll
  for (int s = 0; s < 4; s++)
    qf[s] = *(const bf16x8*)(qbase + (size_t)(qw0 + l15) * rs + s * 32 + quad * 8);

  // staging map: this thread handles K/V rows kk = i*16 + srow, d-octet soct
  int srow = tid >> 4;  // 0..15
  int soct = l15;       // d = soct*8 + j

  f32x4 o[8] = {};
  float mrow[4] = {-INFINITY, -INFINITY, -INFINITY, -INFINITY};
  float lrow[4] = {0.f, 0.f, 0.f, 0.f};

  int nkt = qb + 1;
  bf16x8 kreg[4], vreg[4];
#pragma unroll
  for (int i = 0; i < 4; i++) {
    int kk = i * 16 + srow;
    kreg[i] = *(const bf16x8*)(kbase + (size_t)kk * rs + soct * 8);
    vreg[i] = *(const bf16x8*)(vbase + (size_t)kk * rs + soct * 8);
  }

  for (int kt = 0; kt < nkt; kt++) {
    int k0 = kt * 64;
    __syncthreads();  // protect LDS from previous tile's readers
#pragma unroll
    for (int i = 0; i < 4; i++) {
      int kk = i * 16 + srow;
      *(bf16x8*)&Kls[kk][soct * 8] = kreg[i];
      // V^T with octet rotation: elem (d, kk) at col ((kk>>3 + d>>3)&7)*8 + (kk&7)
      int rotbase = ((kk >> 3) + soct) & 7;
#pragma unroll
      for (int j = 0; j < 8; j++)
        Vls[soct * 8 + j][rotbase * 8 + (kk & 7)] = vreg[i][j];
    }
    __syncthreads();
    // prefetch next tile's K/V into registers (latency hidden under compute)
    if (kt + 1 < nkt) {
#pragma unroll
      for (int i = 0; i < 4; i++) {
        int kk = k0 + 64 + i * 16 + srow;
        kreg[i] = *(const bf16x8*)(kbase + (size_t)kk * rs + soct * 8);
        vreg[i] = *(const bf16x8*)(vbase + (size_t)kk * rs + soct * 8);
      }
    }

    int kmax_off = qw0 + 15 - k0;  // wave-uniform, >= 15

    // S = Q K^T (skip fully-masked 16-col tiles)
    f32x4 sa[4] = {};
#pragma unroll
    for (int nt = 0; nt < 4; nt++) {
      if (nt * 16 <= kmax_off) {
#pragma unroll
        for (int st = 0; st < 4; st++) {
          bf16x8 kf = *(const bf16x8*)&Kls[nt * 16 + l15][st * 32 + quad * 8];
          sa[nt] = __builtin_amdgcn_mfma_f32_16x16x32_bf16(qf[st], kf, sa[nt], 0, 0, 0);
        }
      }
    }

    // R band = Q @ Er^T; tiles n: col c = n*16+l15 of R, Er row m_base+c.
    // Only c <= kmax_off consumed unmasked -> tiles n*16 <= kmax_off, +1 for pair.
    int m_base = 1008 - qw0 + k0;
    int ntR = (kmax_off >> 4) + 1;
    if (ntR > 4) ntR = 4;
    f32x4 rr[5] = {};
#pragma unroll
    for (int n = 0; n < 5; n++) {
      if (n <= ntR) {
        int mr = m_base + n * 16 + l15;
        mr = mr < 0 ? 0 : (mr > 1023 ? 1023 : mr);
#pragma unroll
        for (int st = 0; st < 4; st++) {
          bf16x8 ef = *(const bf16x8*)(Erb + (size_t)mr * HSS + st * 32 + quad * 8);
          rr[n] = __builtin_amdgcn_mfma_f32_16x16x32_bf16(qf[st], ef, rr[n], 0, 0, 0);
        }
      }
    }

    // combine S + diagonal-gathered R (in place into sa), scale, mask; row max
    float pmx[4] = {-INFINITY, -INFINITY, -INFINITY, -INFINITY};
#pragma unroll
    for (int rg = 0; rg < 4; rg++) {
      int qloc = quad * 4 + rg;
      int t = 15 - qloc + l15;              // 0..30; c = nt*16 + t
      int src = (lane & 48) | (t & 15);     // same quad-row, rotated col
      float shv[5];
#pragma unroll
      for (int n = 0; n < 5; n++)
        shv[n] = (n <= ntR) ? __shfl(rr[n][rg], src) : 0.f;
#pragma unroll
      for (int nt = 0; nt < 4; nt++) {
        if (nt * 16 <= kmax_off) {
          float rv = (t & 16) ? shv[nt + 1] : shv[nt];
          float v = (sa[nt][rg] + rv) * SCALE;
          int kg = k0 + nt * 16 + l15;
          v = (kg <= qw0 + qloc) ? v : -INFINITY;
          sa[nt][rg] = v;
          pmx[rg] = fmaxf(pmx[rg], v);
        } else {
          sa[nt][rg] = -INFINITY;
        }
      }
    }

    // online softmax (per 16-lane row group; no cross-wave data)
#pragma unroll
    for (int rg = 0; rg < 4; rg++) {
      float v = pmx[rg];
      v = fmaxf(v, __shfl_xor(v, 1));
      v = fmaxf(v, __shfl_xor(v, 2));
      v = fmaxf(v, __shfl_xor(v, 4));
      v = fmaxf(v, __shfl_xor(v, 8));
      float mnew = fmaxf(mrow[rg], v);
      float alpha = __expf(mrow[rg] - mnew);
      mrow[rg] = mnew;
      lrow[rg] *= alpha;
#pragma unroll
      for (int nt = 0; nt < 8; nt++) o[nt][rg] *= alpha;
      pmx[rg] = mnew;
    }
    float ls[4] = {0.f, 0.f, 0.f, 0.f};
#pragma unroll
    for (int nt = 0; nt < 4; nt++)
#pragma unroll
      for (int rg = 0; rg < 4; rg++) {
        float p = __expf(sa[nt][rg] - pmx[rg]);
        ls[rg] += p;
        Pls[wave][quad * 4 + rg][nt * 16 + l15] = (bf16)p;
      }
#pragma unroll
    for (int rg = 0; rg < 4; rg++) {
      float v = ls[rg];
      v += __shfl_xor(v, 1);
      v += __shfl_xor(v, 2);
      v += __shfl_xor(v, 4);
      v += __shfl_xor(v, 8);
      lrow[rg] += v;
    }
    // no barrier: Pls is per-wave (lgkmcnt covers same-wave RAW)

    // O += P @ V
    bf16x8 pf[2];
#pragma unroll
    for (int s2 = 0; s2 < 2; s2++)
      pf[s2] = *(const bf16x8*)&Pls[wave][l15][s2 * 32 + quad * 8];
#pragma unroll
    for (int nt = 0; nt < 8; nt++) {
#pragma unroll
      for (int s2 = 0; s2 < 2; s2++) {
        if (s2 * 32 <= kmax_off) {
          int d = nt * 16 + l15;
          int rot = ((s2 * 4 + quad) + (d >> 3)) & 7;
          bf16x8 vf = *(const bf16x8*)&Vls[d][rot * 8];
          o[nt] = __builtin_amdgcn_mfma_f32_16x16x32_bf16(pf[s2], vf, o[nt], 0, 0, 0);
        }
      }
    }
  }

  // finalize: O / l -> y[b, q, h*128 + d] bf16
#pragma unroll
  for (int rg = 0; rg < 4; rg++) {
    float inv = 1.0f / lrow[rg];
    int qg = qw0 + quad * 4 + rg;
    bf16* yr = y + ((size_t)b * LL + qg) * DD + h * HSS;
#pragma unroll
    for (int nt = 0; nt < 8; nt++) yr[nt * 16 + l15] = (bf16)(o[nt][rg] * inv);
  }
}

// ---------------------------------------------------------------------------
extern "C" void kernel_launch(void* const* d_in, const int* in_sizes, int n_in,
                              void* d_out, int out_size, void* d_ws, size_t ws_size,
                              hipStream_t stream) {
  const float* x = (const float*)d_in[0];
  const float* W_qkv = (const float*)d_in[1];
  const float* b_qkv = (const float*)d_in[2];
  const float* W_o = (const float*)d_in[3];
  const float* b_o = (const float*)d_in[4];
  const float* Er = (const float*)d_in[5];
  const float* ln1_g = (const float*)d_in[6];
  const float* ln1_b = (const float*)d_in[7];
  const float* ln2_g = (const float*)d_in[8];
  const float* ln2_b = (const float*)d_in[9];
  const float* W_fc = (const float*)d_in[10];
  const float* b_fc = (const float*)d_in[11];
  const float* W_proj = (const float*)d_in[12];
  const float* b_proj = (const float*)d_in[13];
  float* out = (float*)d_out;

  char* p = (char*)d_ws;
  auto alloc = [&](size_t bytes) {
    char* r = p;
    p += (bytes + 255) & ~(size_t)255;
    return r;
  };
  bf16* Wt_qkv = (bf16*)alloc((size_t)3072 * 1024 * 2);
  bf16* Wt_o   = (bf16*)alloc((size_t)1024 * 1024 * 2);
  bf16* Wt_fc  = (bf16*)alloc((size_t)4096 * 1024 * 2);
  bf16* Wt_pr  = (bf16*)alloc((size_t)1024 * 4096 * 2);
  bf16* Erb    = (bf16*)alloc((size_t)1024 * 128 * 2);
  bf16* xn     = (bf16*)alloc((size_t)8192 * 1024 * 2);
  bf16* qkvb   = (bf16*)alloc((size_t)8192 * 3072 * 2);  // also reused as hb
  bf16* yb     = (bf16*)alloc((size_t)8192 * 1024 * 2);
  float* x2    = (float*)alloc((size_t)8192 * 1024 * 4);
  bf16* hb     = qkvb;  // qkvb+yb dead after attn/out-proj; h needs 64MB

  // weight prep
  transpose_cast_kernel<<<dim3(3072 / 32, 1024 / 32), dim3(32, 8), 0, stream>>>(W_qkv, Wt_qkv, 1024, 3072);
  transpose_cast_kernel<<<dim3(1024 / 32, 1024 / 32), dim3(32, 8), 0, stream>>>(W_o, Wt_o, 1024, 1024);
  transpose_cast_kernel<<<dim3(4096 / 32, 1024 / 32), dim3(32, 8), 0, stream>>>(W_fc, Wt_fc, 1024, 4096);
  transpose_cast_kernel<<<dim3(1024 / 32, 4096 / 32), dim3(32, 8), 0, stream>>>(W_proj, Wt_pr, 4096, 1024);
  cast_bf16_kernel<<<512, 256, 0, stream>>>(Er, Erb, 1024 * 128);

  // block
  ln_kernel<<<8192, 256, 0, stream>>>(x, ln1_g, ln1_b, xn);
  gemm_kernel<0><<<dim3(24, 64), 256, 0, stream>>>(xn, Wt_qkv, b_qkv, nullptr, qkvb, 8192, 3072, 1024);
  flash_kernel<<<dim3(16, 8, 8), 256, 0, stream>>>(qkvb, Erb, yb);
  gemm_kernel<2><<<dim3(8, 64), 256, 0, stream>>>(yb, Wt_o, b_o, x, x2, 8192, 1024, 1024);
  ln_kernel<<<8192, 256, 0, stream>>>(x2, ln2_g, ln2_b, xn);
  gemm_kernel<1><<<dim3(32, 64), 256, 0, stream>>>(xn, Wt_fc, b_fc, nullptr, hb, 8192, 4096, 1024);
  gemm_kernel<2><<<dim3(8, 64), 256, 0, stream>>>(hb, Wt_pr, b_proj, x2, out, 8192, 1024, 4096);
}

// Round 4
// 833.409 us; speedup vs baseline: 1.1536x; 1.1536x over previous
//
#include <hip/hip_runtime.h>
#include <hip/hip_bf16.h>
#include <math.h>

// Problem constants
#define BB 8
#define LL 1024
#define DD 1024
#define FF 4096
#define NHH 8
#define HSS 128
#define SCALE 0.08838834764831845f  // 1/sqrt(128)
#define TRI(qi, kt) ((qi) * ((qi) + 1) / 2 + (kt))

typedef __bf16 bf16;
typedef __bf16 bf16x8 __attribute__((ext_vector_type(8)));
typedef float f32x4 __attribute__((ext_vector_type(4)));
typedef _Float16 f16;
typedef _Float16 f16x4 __attribute__((ext_vector_type(4)));

__device__ inline void async_copy16(const void* g, void* l) {
  __builtin_amdgcn_global_load_lds(
      (const __attribute__((address_space(1))) unsigned int*)g,
      (__attribute__((address_space(3))) unsigned int*)l, 16, 0, 0);
}

// ---------------------------------------------------------------------------
// Transpose + cast: W [K][N] fp32 -> Wt [N][K] bf16
// ---------------------------------------------------------------------------
__global__ __launch_bounds__(256)
void transpose_cast_kernel(const float* __restrict__ W, bf16* __restrict__ Wt,
                           int K, int N) {
  __shared__ float tile[32][33];
  int n0 = blockIdx.x * 32, k0 = blockIdx.y * 32;
  int tx = threadIdx.x, ty = threadIdx.y;
#pragma unroll
  for (int i = 0; i < 32; i += 8)
    tile[ty + i][tx] = W[(size_t)(k0 + ty + i) * N + n0 + tx];
  __syncthreads();
#pragma unroll
  for (int i = 0; i < 32; i += 8)
    Wt[(size_t)(n0 + ty + i) * K + k0 + tx] = (bf16)tile[tx][ty + i];
}

__global__ __launch_bounds__(256)
void cast_bf16_kernel(const float* __restrict__ src, bf16* __restrict__ dst, int n) {
  int i = blockIdx.x * blockDim.x + threadIdx.x;
  if (i < n) dst[i] = (bf16)src[i];
}

// ---------------------------------------------------------------------------
// LayerNorm: x [8192][1024] fp32 -> out bf16
// ---------------------------------------------------------------------------
__global__ __launch_bounds__(256)
void ln_kernel(const float* __restrict__ x, const float* __restrict__ g,
               const float* __restrict__ bta, bf16* __restrict__ out) {
  int row = blockIdx.x;
  int tid = threadIdx.x;
  const float4 v = ((const float4*)(x + (size_t)row * DD))[tid];
  float s = v.x + v.y + v.z + v.w;
  float s2 = v.x * v.x + v.y * v.y + v.z * v.z + v.w * v.w;
#pragma unroll
  for (int o = 32; o > 0; o >>= 1) {
    s += __shfl_down(s, o);
    s2 += __shfl_down(s2, o);
  }
  __shared__ float a1[4], a2[4];
  int wave = tid >> 6;
  if ((tid & 63) == 0) { a1[wave] = s; a2[wave] = s2; }
  __syncthreads();
  s = a1[0] + a1[1] + a1[2] + a1[3];
  s2 = a2[0] + a2[1] + a2[2] + a2[3];
  float mu = s * (1.0f / DD);
  float rstd = rsqrtf(s2 * (1.0f / DD) - mu * mu + 1e-5f);
  float4 gv = ((const float4*)g)[tid];
  float4 bv = ((const float4*)bta)[tid];
  bf16* o4 = out + (size_t)row * DD + tid * 4;
  o4[0] = (bf16)((v.x - mu) * rstd * gv.x + bv.x);
  o4[1] = (bf16)((v.y - mu) * rstd * gv.y + bv.y);
  o4[2] = (bf16)((v.z - mu) * rstd * gv.z + bv.z);
  o4[3] = (bf16)((v.w - mu) * rstd * gv.w + bv.w);
}

// ---------------------------------------------------------------------------
// GEMM: C[M][N] = A[M][K](bf16) * Bt[N][K](bf16)^T + bias
// EPI 0: -> bf16   EPI 1: gelu -> bf16   EPI 2: + res(fp32) -> fp32
// ---------------------------------------------------------------------------
template <int EPI>
__global__ __launch_bounds__(256)
void gemm_kernel(const bf16* __restrict__ A, const bf16* __restrict__ Bt,
                 const float* __restrict__ bias, const float* __restrict__ res,
                 void* __restrict__ Cout, int M, int N, int K) {
  __shared__ bf16 Als[128 * 32];
  __shared__ bf16 Bls[128 * 32];
  int tid = threadIdx.x;
  int wave = tid >> 6, lane = tid & 63;
  int l15 = lane & 15, quad = lane >> 4;
  int m0 = blockIdx.y * 128, n0 = blockIdx.x * 128;
  int wm = (wave >> 1) * 64, wn = (wave & 1) * 64;
  f32x4 acc[4][4] = {};

  for (int k0 = 0; k0 < K; k0 += 32) {
    __syncthreads();
#pragma unroll
    for (int i = 0; i < 2; i++) {
      int t = i * 256 + tid;
      int row = t >> 2, kc = (t & 3) << 3;
      async_copy16(A + (size_t)(m0 + row) * K + k0 + kc, &Als[t * 8]);
      async_copy16(Bt + (size_t)(n0 + row) * K + k0 + kc, &Bls[t * 8]);
    }
    __syncthreads();
    bf16x8 af[4], bfr[4];
#pragma unroll
    for (int mt = 0; mt < 4; mt++)
      af[mt] = *(const bf16x8*)&Als[(wm + mt * 16 + l15) * 32 + quad * 8];
#pragma unroll
    for (int nt = 0; nt < 4; nt++)
      bfr[nt] = *(const bf16x8*)&Bls[(wn + nt * 16 + l15) * 32 + quad * 8];
#pragma unroll
    for (int mt = 0; mt < 4; mt++)
#pragma unroll
      for (int nt = 0; nt < 4; nt++)
        acc[mt][nt] = __builtin_amdgcn_mfma_f32_16x16x32_bf16(af[mt], bfr[nt],
                                                              acc[mt][nt], 0, 0, 0);
  }

#pragma unroll
  for (int mt = 0; mt < 4; mt++) {
#pragma unroll
    for (int nt = 0; nt < 4; nt++) {
      int col = n0 + wn + nt * 16 + l15;
      float bv = bias[col];
#pragma unroll
      for (int r = 0; r < 4; r++) {
        int row = m0 + wm + mt * 16 + quad * 4 + r;
        float v = acc[mt][nt][r] + bv;
        if (EPI == 1) v = 0.5f * v * (1.0f + erff(v * 0.7071067811865475f));
        if (EPI == 2) {
          v += res[(size_t)row * N + col];
          ((float*)Cout)[(size_t)row * N + col] = v;
        } else {
          ((bf16*)Cout)[(size_t)row * N + col] = (bf16)v;
        }
      }
    }
  }
}

// ---------------------------------------------------------------------------
// pack_kv: per (b,h,kt) repack K into [kk][chunk^swizzle] and V transposed
// into [d][chunk^swizzle], 16B chunks, so flash can DMA-stage with
// global_load_lds and read fragments conflict-free.
// ---------------------------------------------------------------------------
__global__ __launch_bounds__(256)
void pack_kv_kernel(const bf16* __restrict__ qkv, bf16* __restrict__ Kpack,
                    bf16* __restrict__ Vpack) {
  __shared__ bf16 Vst[64][132];  // raw V tile [kk][d], padded
  int kt = blockIdx.x, h = blockIdx.y, b = blockIdx.z;
  int tid = threadIdx.x;
  const size_t rs = 3 * DD;
  const bf16* kb = qkv + (size_t)b * LL * rs + (size_t)(kt * 64) * rs + DD + h * HSS;
  const bf16* vb = kb + DD;
  bf16* kp = Kpack + ((size_t)(b * NHH + h) * 16 + kt) * (64 * 128);
  bf16* vp = Vpack + ((size_t)(b * NHH + h) * 16 + kt) * (128 * 64);
#pragma unroll
  for (int i = 0; i < 4; i++) {
    int u = i * 256 + tid;
    int kk = u >> 4, c = u & 15;
    // K: element (kk,d): chunk c=d>>3 stored at (c ^ (kk&15))
    bf16x8 kv = *(const bf16x8*)(kb + (size_t)kk * rs + c * 8);
    *(bf16x8*)(kp + kk * 128 + ((c ^ kk) & 15) * 8) = kv;
    // V raw stage for transpose
    *(bf16x8*)&Vst[kk][c * 8] = *(const bf16x8*)(vb + (size_t)kk * rs + c * 8);
  }
  __syncthreads();
#pragma unroll
  for (int i = 0; i < 4; i++) {
    int u = i * 256 + tid;
    int d = u >> 3, c = u & 7;  // V^T row d, kk-chunk c (kk = c*8+j)
    bf16x8 t;
#pragma unroll
    for (int j = 0; j < 8; j++) t[j] = Vst[c * 8 + j][d];
    *(bf16x8*)(vp + d * 64 + ((c ^ (d & 7))) * 8) = t;
  }
}

// ---------------------------------------------------------------------------
// relband: SrelT band = skew(Q @ Er^T), stored transposed [k][q] in f16,
// triangular 64x64 tile packing: tile(qi,kt) at TRI(qi,kt)*4096.
// Only k<=q slots written (flash masks the rest).
// ---------------------------------------------------------------------------
__global__ __launch_bounds__(256)
void relband_kernel(const bf16* __restrict__ qkv, const bf16* __restrict__ Erb,
                    f16* __restrict__ band) {
  int qi = 15 - blockIdx.x;  // LPT
  int h = blockIdx.y, b = blockIdx.z;
  int tid = threadIdx.x, wave = tid >> 6, lane = tid & 63;
  int l15 = lane & 15, quad = lane >> 4;
  int q0w = qi * 64 + wave * 16;
  const size_t rs = 3 * DD;
  const bf16* qbase = qkv + (size_t)b * LL * rs + h * HSS;
  bf16x8 qf[4];
#pragma unroll
  for (int st = 0; st < 4; st++)
    qf[st] = *(const bf16x8*)(qbase + (size_t)(q0w + l15) * rs + st * 32 + quad * 8);
  f16* bnd = band + (size_t)(b * NHH + h) * (136 * 4096);

  for (int kt = 0; kt <= qi; kt++) {
    int mb = 1008 - q0w + 64 * kt;
    f16* tb = bnd + (size_t)TRI(qi, kt) * 4096;
#pragma unroll
    for (int mt = 0; mt < 5; mt++) {
      int m = mb + mt * 16 + l15;
      int mr = m < 0 ? 0 : (m > 1023 ? 1023 : m);
      f32x4 rr = {};
#pragma unroll
      for (int st = 0; st < 4; st++) {
        bf16x8 ef = *(const bf16x8*)(Erb + (size_t)mr * HSS + st * 32 + quad * 8);
        rr = __builtin_amdgcn_mfma_f32_16x16x32_bf16(qf[st], ef, rr, 0, 0, 0);
      }
#pragma unroll
      for (int rg = 0; rg < 4; rg++) {
        int qloc = wave * 16 + quad * 4 + rg;        // q local to qi-block
        int k = (mb + mt * 16 + l15) - 1023 + qi * 64 + qloc;  // global k
        int kl = k - kt * 64;
        if (kl >= 0 && kl < 64 && k <= qi * 64 + qloc)
          tb[kl * 64 + qloc] = (f16)rr[rg];
      }
    }
  }
}

// ---------------------------------------------------------------------------
// Flash attention v4: DMA-staged swizzled K/V tiles, precomputed Srel band.
// No global loads in the k-loop besides DMA + L2-hot band frags (all drained
// at one barrier -> no vmcnt entanglement). Block: 4 waves, BQ=64, BK=64.
// ---------------------------------------------------------------------------
__global__ __launch_bounds__(256)
void flash_kernel(const bf16* __restrict__ qkv, const bf16* __restrict__ Kpack,
                  const bf16* __restrict__ Vpack, const f16* __restrict__ band,
                  bf16* __restrict__ y) {
  __shared__ bf16 Kls[64 * 128];  // [kk][chunk^kk swizzle]
  __shared__ bf16 Vls[128 * 64];  // [d][chunk^d swizzle]
  __shared__ bf16 Pls[4][16][72];

  int tid = threadIdx.x, wave = tid >> 6, lane = tid & 63;
  int l15 = lane & 15, quad = lane >> 4;
  int qb = 15 - blockIdx.x;  // LPT
  int h = blockIdx.y, b = blockIdx.z;
  int qw0 = qb * 64 + wave * 16;

  const size_t rs = 3 * DD;
  const bf16* qbase = qkv + (size_t)b * LL * rs + h * HSS;
  const bf16* kp = Kpack + (size_t)(b * NHH + h) * 16 * (64 * 128);
  const bf16* vp = Vpack + (size_t)(b * NHH + h) * 16 * (128 * 64);
  const f16* bnd = band + (size_t)(b * NHH + h) * (136 * 4096);

  bf16x8 qf[4];
#pragma unroll
  for (int st = 0; st < 4; st++)
    qf[st] = *(const bf16x8*)(qbase + (size_t)(qw0 + l15) * rs + st * 32 + quad * 8);

  f32x4 o[8] = {};
  float mrow[4] = {-INFINITY, -INFINITY, -INFINITY, -INFINITY};
  float lrow[4] = {0.f, 0.f, 0.f, 0.f};

  int nkt = qb + 1;
  for (int kt = 0; kt < nkt; kt++) {
    int k0 = kt * 64;
    int kmax_off = qw0 + 15 - k0;  // wave-uniform
    __syncthreads();  // prev tile's LDS readers done
    // DMA stage K (16KB) + V^T (16KB); per wave 4+4 instrs, lane-linear
    {
      const bf16* ks = kp + (size_t)kt * (64 * 128);
      const bf16* vs = vp + (size_t)kt * (128 * 64);
#pragma unroll
      for (int i = 0; i < 4; i++) {
        int off = (wave * 4 + i) * 512 + lane * 8;
        async_copy16(ks + off, &Kls[off]);
        async_copy16(vs + off, &Vls[off]);
      }
    }
    // Srel band fragments (L2/L3-hot)
    const f16* tb = bnd + (size_t)TRI(qb, kt) * 4096;
    f16x4 srl[4] = {};
#pragma unroll
    for (int nt = 0; nt < 4; nt++)
      if (nt * 16 <= kmax_off)
        srl[nt] = *(const f16x4*)(tb + (nt * 16 + l15) * 64 + wave * 16 + quad * 4);
    __syncthreads();  // drains DMA (vmcnt0) once per tile

    // S = Q K^T
    f32x4 sa[4] = {};
#pragma unroll
    for (int nt = 0; nt < 4; nt++) {
      if (nt * 16 <= kmax_off) {
        int kk = nt * 16 + l15;
#pragma unroll
        for (int st = 0; st < 4; st++) {
          bf16x8 kf = *(const bf16x8*)&Kls[kk * 128 + (((st * 4 + quad) ^ l15) & 15) * 8];
          sa[nt] = __builtin_amdgcn_mfma_f32_16x16x32_bf16(qf[st], kf, sa[nt], 0, 0, 0);
        }
      }
    }

    // combine + mask + row max
    float pmx[4] = {-INFINITY, -INFINITY, -INFINITY, -INFINITY};
#pragma unroll
    for (int nt = 0; nt < 4; nt++) {
      if (nt * 16 <= kmax_off) {
        int kg = k0 + nt * 16 + l15;
#pragma unroll
        for (int rg = 0; rg < 4; rg++) {
          int qg = qw0 + quad * 4 + rg;
          float v = (sa[nt][rg] + (float)srl[nt][rg]) * SCALE;
          v = (kg <= qg) ? v : -INFINITY;
          sa[nt][rg] = v;
          pmx[rg] = fmaxf(pmx[rg], v);
        }
      } else {
#pragma unroll
        for (int rg = 0; rg < 4; rg++) sa[nt][rg] = -INFINITY;
      }
    }

    // online softmax (per 16-lane row group)
#pragma unroll
    for (int rg = 0; rg < 4; rg++) {
      float v = pmx[rg];
      v = fmaxf(v, __shfl_xor(v, 1));
      v = fmaxf(v, __shfl_xor(v, 2));
      v = fmaxf(v, __shfl_xor(v, 4));
      v = fmaxf(v, __shfl_xor(v, 8));
      float mnew = fmaxf(mrow[rg], v);
      float alpha = __expf(mrow[rg] - mnew);
      mrow[rg] = mnew;
      lrow[rg] *= alpha;
#pragma unroll
      for (int nt = 0; nt < 8; nt++) o[nt][rg] *= alpha;
      pmx[rg] = mnew;
    }
    float ls[4] = {0.f, 0.f, 0.f, 0.f};
#pragma unroll
    for (int nt = 0; nt < 4; nt++)
#pragma unroll
      for (int rg = 0; rg < 4; rg++) {
        float p = __expf(sa[nt][rg] - pmx[rg]);
        ls[rg] += p;
        Pls[wave][quad * 4 + rg][nt * 16 + l15] = (bf16)p;
      }
#pragma unroll
    for (int rg = 0; rg < 4; rg++) {
      float v = ls[rg];
      v += __shfl_xor(v, 1);
      v += __shfl_xor(v, 2);
      v += __shfl_xor(v, 4);
      v += __shfl_xor(v, 8);
      lrow[rg] += v;
    }
    // Pls is per-wave: same-wave DS ordering suffices, no barrier

    // O += P @ V
    bf16x8 pf[2];
#pragma unroll
    for (int s2 = 0; s2 < 2; s2++)
      pf[s2] = *(const bf16x8*)&Pls[wave][l15][s2 * 32 + quad * 8];
#pragma unroll
    for (int nt = 0; nt < 8; nt++) {
      int d = nt * 16 + l15;
#pragma unroll
      for (int s2 = 0; s2 < 2; s2++) {
        if (s2 * 32 <= kmax_off) {
          bf16x8 vf = *(const bf16x8*)&Vls[d * 64 + (((s2 * 4 + quad) ^ (l15 & 7)) & 7) * 8];
          o[nt] = __builtin_amdgcn_mfma_f32_16x16x32_bf16(pf[s2], vf, o[nt], 0, 0, 0);
        }
      }
    }
  }

  // finalize: O / l -> y[b, q, h*128 + d] bf16
#pragma unroll
  for (int rg = 0; rg < 4; rg++) {
    float inv = 1.0f / lrow[rg];
    int qg = qw0 + quad * 4 + rg;
    bf16* yr = y + ((size_t)b * LL + qg) * DD + h * HSS;
#pragma unroll
    for (int nt = 0; nt < 8; nt++) yr[nt * 16 + l15] = (bf16)(o[nt][rg] * inv);
  }
}

// ---------------------------------------------------------------------------
extern "C" void kernel_launch(void* const* d_in, const int* in_sizes, int n_in,
                              void* d_out, int out_size, void* d_ws, size_t ws_size,
                              hipStream_t stream) {
  const float* x = (const float*)d_in[0];
  const float* W_qkv = (const float*)d_in[1];
  const float* b_qkv = (const float*)d_in[2];
  const float* W_o = (const float*)d_in[3];
  const float* b_o = (const float*)d_in[4];
  const float* Er = (const float*)d_in[5];
  const float* ln1_g = (const float*)d_in[6];
  const float* ln1_b = (const float*)d_in[7];
  const float* ln2_g = (const float*)d_in[8];
  const float* ln2_b = (const float*)d_in[9];
  const float* W_fc = (const float*)d_in[10];
  const float* b_fc = (const float*)d_in[11];
  const float* W_proj = (const float*)d_in[12];
  const float* b_proj = (const float*)d_in[13];
  float* out = (float*)d_out;

  char* p = (char*)d_ws;
  auto alloc = [&](size_t bytes) {
    char* r = p;
    p += (bytes + 255) & ~(size_t)255;
    return r;
  };
  bf16* Wt_qkv = (bf16*)alloc((size_t)3072 * 1024 * 2);
  bf16* Wt_o   = (bf16*)alloc((size_t)1024 * 1024 * 2);
  bf16* Wt_fc  = (bf16*)alloc((size_t)4096 * 1024 * 2);
  bf16* Wt_pr  = (bf16*)alloc((size_t)1024 * 4096 * 2);
  bf16* Erb    = (bf16*)alloc((size_t)1024 * 128 * 2);
  bf16* xn     = (bf16*)alloc((size_t)8192 * 1024 * 2);
  bf16* qkvb   = (bf16*)alloc((size_t)8192 * 3072 * 2);  // + yb = hb region
  bf16* yb     = (bf16*)alloc((size_t)8192 * 1024 * 2);  // must follow qkvb
  bf16* Kpack  = (bf16*)alloc((size_t)64 * 16 * 64 * 128 * 2);
  bf16* Vpack  = (bf16*)alloc((size_t)64 * 16 * 128 * 64 * 2);
  f16*  band   = (f16*)alloc((size_t)64 * 136 * 4096 * 2);  // 71.3 MB
  float* x2    = (float*)band;  // alias: band dead before x2 is written
  bf16* hb     = qkvb;          // spans qkvb+yb (66MB >= 64MB needed)

  // weight prep
  transpose_cast_kernel<<<dim3(3072 / 32, 1024 / 32), dim3(32, 8), 0, stream>>>(W_qkv, Wt_qkv, 1024, 3072);
  transpose_cast_kernel<<<dim3(1024 / 32, 1024 / 32), dim3(32, 8), 0, stream>>>(W_o, Wt_o, 1024, 1024);
  transpose_cast_kernel<<<dim3(4096 / 32, 1024 / 32), dim3(32, 8), 0, stream>>>(W_fc, Wt_fc, 1024, 4096);
  transpose_cast_kernel<<<dim3(1024 / 32, 4096 / 32), dim3(32, 8), 0, stream>>>(W_proj, Wt_pr, 4096, 1024);
  cast_bf16_kernel<<<512, 256, 0, stream>>>(Er, Erb, 1024 * 128);

  // block
  ln_kernel<<<8192, 256, 0, stream>>>(x, ln1_g, ln1_b, xn);
  gemm_kernel<0><<<dim3(24, 64), 256, 0, stream>>>(xn, Wt_qkv, b_qkv, nullptr, qkvb, 8192, 3072, 1024);
  pack_kv_kernel<<<dim3(16, 8, 8), 256, 0, stream>>>(qkvb, Kpack, Vpack);
  relband_kernel<<<dim3(16, 8, 8), 256, 0, stream>>>(qkvb, Erb, band);
  flash_kernel<<<dim3(16, 8, 8), 256, 0, stream>>>(qkvb, Kpack, Vpack, band, yb);
  gemm_kernel<2><<<dim3(8, 64), 256, 0, stream>>>(yb, Wt_o, b_o, x, x2, 8192, 1024, 1024);
  ln_kernel<<<8192, 256, 0, stream>>>(x2, ln2_g, ln2_b, xn);
  gemm_kernel<1><<<dim3(32, 64), 256, 0, stream>>>(xn, Wt_fc, b_fc, nullptr, hb, 8192, 4096, 1024);
  gemm_kernel<2><<<dim3(8, 64), 256, 0, stream>>>(hb, Wt_pr, b_proj, x2, out, 8192, 1024, 4096);
}

// Round 5
// 789.143 us; speedup vs baseline: 1.2184x; 1.0561x over previous
//
#include <hip/hip_runtime.h>
#include <hip/hip_bf16.h>
#include <math.h>

// Problem constants
#define BB 8
#define LL 1024
#define DD 1024
#define FF 4096
#define NHH 8
#define HSS 128
#define SCALE 0.08838834764831845f  // 1/sqrt(128)
#define TRI(qi, kt) ((qi) * ((qi) + 1) / 2 + (kt))

typedef __bf16 bf16;
typedef __bf16 bf16x8 __attribute__((ext_vector_type(8)));
typedef float f32x4 __attribute__((ext_vector_type(4)));
typedef _Float16 f16;
typedef _Float16 f16x4 __attribute__((ext_vector_type(4)));

__device__ inline void async_copy16(const void* g, void* l) {
  __builtin_amdgcn_global_load_lds(
      (const __attribute__((address_space(1))) unsigned int*)g,
      (__attribute__((address_space(3))) unsigned int*)l, 16, 0, 0);
}

// ---------------------------------------------------------------------------
// Transpose + cast: W [K][N] fp32 -> Wt [N][K] bf16
// ---------------------------------------------------------------------------
__global__ __launch_bounds__(256)
void transpose_cast_kernel(const float* __restrict__ W, bf16* __restrict__ Wt,
                           int K, int N) {
  __shared__ float tile[32][33];
  int n0 = blockIdx.x * 32, k0 = blockIdx.y * 32;
  int tx = threadIdx.x, ty = threadIdx.y;
#pragma unroll
  for (int i = 0; i < 32; i += 8)
    tile[ty + i][tx] = W[(size_t)(k0 + ty + i) * N + n0 + tx];
  __syncthreads();
#pragma unroll
  for (int i = 0; i < 32; i += 8)
    Wt[(size_t)(n0 + ty + i) * K + k0 + tx] = (bf16)tile[tx][ty + i];
}

__global__ __launch_bounds__(256)
void cast_bf16_kernel(const float* __restrict__ src, bf16* __restrict__ dst, int n) {
  int i = blockIdx.x * blockDim.x + threadIdx.x;
  if (i < n) dst[i] = (bf16)src[i];
}

// ---------------------------------------------------------------------------
// LayerNorm: x [8192][1024] fp32 -> out bf16
// ---------------------------------------------------------------------------
__global__ __launch_bounds__(256)
void ln_kernel(const float* __restrict__ x, const float* __restrict__ g,
               const float* __restrict__ bta, bf16* __restrict__ out) {
  int row = blockIdx.x;
  int tid = threadIdx.x;
  const float4 v = ((const float4*)(x + (size_t)row * DD))[tid];
  float s = v.x + v.y + v.z + v.w;
  float s2 = v.x * v.x + v.y * v.y + v.z * v.z + v.w * v.w;
#pragma unroll
  for (int o = 32; o > 0; o >>= 1) {
    s += __shfl_down(s, o);
    s2 += __shfl_down(s2, o);
  }
  __shared__ float a1[4], a2[4];
  int wave = tid >> 6;
  if ((tid & 63) == 0) { a1[wave] = s; a2[wave] = s2; }
  __syncthreads();
  s = a1[0] + a1[1] + a1[2] + a1[3];
  s2 = a2[0] + a2[1] + a2[2] + a2[3];
  float mu = s * (1.0f / DD);
  float rstd = rsqrtf(s2 * (1.0f / DD) - mu * mu + 1e-5f);
  float4 gv = ((const float4*)g)[tid];
  float4 bv = ((const float4*)bta)[tid];
  bf16* o4 = out + (size_t)row * DD + tid * 4;
  o4[0] = (bf16)((v.x - mu) * rstd * gv.x + bv.x);
  o4[1] = (bf16)((v.y - mu) * rstd * gv.y + bv.y);
  o4[2] = (bf16)((v.z - mu) * rstd * gv.z + bv.z);
  o4[3] = (bf16)((v.w - mu) * rstd * gv.w + bv.w);
}

// ---------------------------------------------------------------------------
// GEMM: C[M][N] = A[M][K](bf16) * Bt[N][K](bf16)^T + bias
// EPI 0: -> bf16   EPI 1: gelu -> bf16   EPI 2: + res(fp32) -> fp32
// ---------------------------------------------------------------------------
template <int EPI>
__global__ __launch_bounds__(256)
void gemm_kernel(const bf16* __restrict__ A, const bf16* __restrict__ Bt,
                 const float* __restrict__ bias, const float* __restrict__ res,
                 void* __restrict__ Cout, int M, int N, int K) {
  __shared__ bf16 Als[128 * 32];
  __shared__ bf16 Bls[128 * 32];
  int tid = threadIdx.x;
  int wave = tid >> 6, lane = tid & 63;
  int l15 = lane & 15, quad = lane >> 4;
  int m0 = blockIdx.y * 128, n0 = blockIdx.x * 128;
  int wm = (wave >> 1) * 64, wn = (wave & 1) * 64;
  f32x4 acc[4][4] = {};

  for (int k0 = 0; k0 < K; k0 += 32) {
    __syncthreads();
#pragma unroll
    for (int i = 0; i < 2; i++) {
      int t = i * 256 + tid;
      int row = t >> 2, kc = (t & 3) << 3;
      async_copy16(A + (size_t)(m0 + row) * K + k0 + kc, &Als[t * 8]);
      async_copy16(Bt + (size_t)(n0 + row) * K + k0 + kc, &Bls[t * 8]);
    }
    __syncthreads();
    bf16x8 af[4], bfr[4];
#pragma unroll
    for (int mt = 0; mt < 4; mt++)
      af[mt] = *(const bf16x8*)&Als[(wm + mt * 16 + l15) * 32 + quad * 8];
#pragma unroll
    for (int nt = 0; nt < 4; nt++)
      bfr[nt] = *(const bf16x8*)&Bls[(wn + nt * 16 + l15) * 32 + quad * 8];
#pragma unroll
    for (int mt = 0; mt < 4; mt++)
#pragma unroll
      for (int nt = 0; nt < 4; nt++)
        acc[mt][nt] = __builtin_amdgcn_mfma_f32_16x16x32_bf16(af[mt], bfr[nt],
                                                              acc[mt][nt], 0, 0, 0);
  }

#pragma unroll
  for (int mt = 0; mt < 4; mt++) {
#pragma unroll
    for (int nt = 0; nt < 4; nt++) {
      int col = n0 + wn + nt * 16 + l15;
      float bv = bias[col];
#pragma unroll
      for (int r = 0; r < 4; r++) {
        int row = m0 + wm + mt * 16 + quad * 4 + r;
        float v = acc[mt][nt][r] + bv;
        if (EPI == 1) v = 0.5f * v * (1.0f + erff(v * 0.7071067811865475f));
        if (EPI == 2) {
          v += res[(size_t)row * N + col];
          ((float*)Cout)[(size_t)row * N + col] = v;
        } else {
          ((bf16*)Cout)[(size_t)row * N + col] = (bf16)v;
        }
      }
    }
  }
}

// ---------------------------------------------------------------------------
// pack_kv: per (b,h,kt) repack K into [kk][chunk^swizzle] and V transposed
// into [d][chunk^swizzle], 16B chunks, so flash can DMA-stage with
// global_load_lds and read fragments conflict-free.
// ---------------------------------------------------------------------------
__global__ __launch_bounds__(256)
void pack_kv_kernel(const bf16* __restrict__ qkv, bf16* __restrict__ Kpack,
                    bf16* __restrict__ Vpack) {
  __shared__ bf16 Vst[64][132];  // raw V tile [kk][d], padded
  int kt = blockIdx.x, h = blockIdx.y, b = blockIdx.z;
  int tid = threadIdx.x;
  const size_t rs = 3 * DD;
  const bf16* kb = qkv + (size_t)b * LL * rs + (size_t)(kt * 64) * rs + DD + h * HSS;
  const bf16* vb = kb + DD;
  bf16* kp = Kpack + ((size_t)(b * NHH + h) * 16 + kt) * (64 * 128);
  bf16* vp = Vpack + ((size_t)(b * NHH + h) * 16 + kt) * (128 * 64);
#pragma unroll
  for (int i = 0; i < 4; i++) {
    int u = i * 256 + tid;
    int kk = u >> 4, c = u & 15;
    // K: element (kk,d): chunk c=d>>3 stored at (c ^ (kk&15))
    bf16x8 kv = *(const bf16x8*)(kb + (size_t)kk * rs + c * 8);
    *(bf16x8*)(kp + kk * 128 + ((c ^ kk) & 15) * 8) = kv;
    // V raw stage for transpose
    *(bf16x8*)&Vst[kk][c * 8] = *(const bf16x8*)(vb + (size_t)kk * rs + c * 8);
  }
  __syncthreads();
#pragma unroll
  for (int i = 0; i < 4; i++) {
    int u = i * 256 + tid;
    int d = u >> 3, c = u & 7;  // V^T row d, kk-chunk c (kk = c*8+j)
    bf16x8 t;
#pragma unroll
    for (int j = 0; j < 8; j++) t[j] = Vst[c * 8 + j][d];
    *(bf16x8*)(vp + d * 64 + ((c ^ (d & 7))) * 8) = t;
  }
}

// ---------------------------------------------------------------------------
// relband v2: SrelT band = skew(Q @ Er^T) via in-register bpermute gather
// (v2-verified machinery), stored in MFMA C-fragment layout per 16x16
// subtile: addr = TRI(qi,kt)*4096 + (wave*4+nt)*256 + l15*16 + quad*4 + rg.
// Each wave store = 64 lanes x 8B contiguous (512B). Flash loads same layout.
// ---------------------------------------------------------------------------
__global__ __launch_bounds__(256)
void relband_kernel(const bf16* __restrict__ qkv, const bf16* __restrict__ Erb,
                    f16* __restrict__ band) {
  int qi = 15 - blockIdx.x;  // LPT
  int h = blockIdx.y, b = blockIdx.z;
  int tid = threadIdx.x, wave = tid >> 6, lane = tid & 63;
  int l15 = lane & 15, quad = lane >> 4;
  int qw0 = qi * 64 + wave * 16;
  const size_t rs = 3 * DD;
  const bf16* qbase = qkv + (size_t)b * LL * rs + h * HSS;
  bf16x8 qf[4];
#pragma unroll
  for (int st = 0; st < 4; st++)
    qf[st] = *(const bf16x8*)(qbase + (size_t)(qw0 + l15) * rs + st * 32 + quad * 8);
  f16* bnd = band + (size_t)(b * NHH + h) * (136 * 4096);

  for (int kt = 0; kt <= qi; kt++) {
    int k0 = kt * 64;
    int kmax_off = qw0 + 15 - k0;  // wave-uniform, >= 15
    int m_base = 1008 - qw0 + k0;
    int ntR = (kmax_off >> 4) + 1;
    if (ntR > 4) ntR = 4;
    // R tiles in C-layout: rr[n][rg] = R[q=qw0+quad*4+rg][m=m_base+n*16+l15]
    f32x4 rr[5] = {};
#pragma unroll
    for (int n = 0; n < 5; n++) {
      if (n <= ntR) {
        int mr = m_base + n * 16 + l15;
        mr = mr < 0 ? 0 : (mr > 1023 ? 1023 : mr);
#pragma unroll
        for (int st = 0; st < 4; st++) {
          bf16x8 ef = *(const bf16x8*)(Erb + (size_t)mr * HSS + st * 32 + quad * 8);
          rr[n] = __builtin_amdgcn_mfma_f32_16x16x32_bf16(qf[st], ef, rr[n], 0, 0, 0);
        }
      }
    }
    // diagonal gather: Srel[q][k] = R[q][m], m = 1023-q+k  (c = 15-qloc+koff)
    f16x4 sf[4];
#pragma unroll
    for (int rg = 0; rg < 4; rg++) {
      int qloc = quad * 4 + rg;
      int t = 15 - qloc + l15;           // 0..30
      int src = (lane & 48) | (t & 15);  // same quad-row, rotated col
      float shv[5];
#pragma unroll
      for (int n = 0; n < 5; n++)
        shv[n] = (n <= ntR) ? __shfl(rr[n][rg], src) : 0.f;
#pragma unroll
      for (int nt = 0; nt < 4; nt++)
        sf[nt][rg] = (f16)((t & 16) ? shv[nt + 1] : shv[nt]);
    }
    // coalesced fragment store (512B per wave store)
    f16* tb = bnd + (size_t)TRI(qi, kt) * 4096;
#pragma unroll
    for (int nt = 0; nt < 4; nt++)
      if (nt * 16 <= kmax_off)
        *(f16x4*)(tb + (wave * 4 + nt) * 256 + l15 * 16 + quad * 4) = sf[nt];
  }
}

// ---------------------------------------------------------------------------
// Flash attention v5: DMA-staged swizzled K/V tiles, fragment-layout Srel
// band (coalesced f16x4 loads). Block: 4 waves, BQ=64, BK=64.
// ---------------------------------------------------------------------------
__global__ __launch_bounds__(256)
void flash_kernel(const bf16* __restrict__ qkv, const bf16* __restrict__ Kpack,
                  const bf16* __restrict__ Vpack, const f16* __restrict__ band,
                  bf16* __restrict__ y) {
  __shared__ bf16 Kls[64 * 128];  // [kk][chunk^kk swizzle]
  __shared__ bf16 Vls[128 * 64];  // [d][chunk^d swizzle]
  __shared__ bf16 Pls[4][16][72];

  int tid = threadIdx.x, wave = tid >> 6, lane = tid & 63;
  int l15 = lane & 15, quad = lane >> 4;
  int qb = 15 - blockIdx.x;  // LPT
  int h = blockIdx.y, b = blockIdx.z;
  int qw0 = qb * 64 + wave * 16;

  const size_t rs = 3 * DD;
  const bf16* qbase = qkv + (size_t)b * LL * rs + h * HSS;
  const bf16* kp = Kpack + (size_t)(b * NHH + h) * 16 * (64 * 128);
  const bf16* vp = Vpack + (size_t)(b * NHH + h) * 16 * (128 * 64);
  const f16* bnd = band + (size_t)(b * NHH + h) * (136 * 4096);

  bf16x8 qf[4];
#pragma unroll
  for (int st = 0; st < 4; st++)
    qf[st] = *(const bf16x8*)(qbase + (size_t)(qw0 + l15) * rs + st * 32 + quad * 8);

  f32x4 o[8] = {};
  float mrow[4] = {-INFINITY, -INFINITY, -INFINITY, -INFINITY};
  float lrow[4] = {0.f, 0.f, 0.f, 0.f};

  int nkt = qb + 1;
  for (int kt = 0; kt < nkt; kt++) {
    int k0 = kt * 64;
    int kmax_off = qw0 + 15 - k0;  // wave-uniform
    __syncthreads();  // prev tile's LDS readers done
    // DMA stage K (16KB) + V^T (16KB); per wave 4+4 instrs, lane-linear
    {
      const bf16* ks = kp + (size_t)kt * (64 * 128);
      const bf16* vs = vp + (size_t)kt * (128 * 64);
#pragma unroll
      for (int i = 0; i < 4; i++) {
        int off = (wave * 4 + i) * 512 + lane * 8;
        async_copy16(ks + off, &Kls[off]);
        async_copy16(vs + off, &Vls[off]);
      }
    }
    // Srel band fragments, C-layout match, 512B/wave coalesced (L2/L3-hot)
    const f16* tb = bnd + (size_t)TRI(qb, kt) * 4096;
    f16x4 srl[4] = {};
#pragma unroll
    for (int nt = 0; nt < 4; nt++)
      if (nt * 16 <= kmax_off)
        srl[nt] = *(const f16x4*)(tb + (wave * 4 + nt) * 256 + l15 * 16 + quad * 4);
    __syncthreads();  // drains DMA (vmcnt0) once per tile

    // S = Q K^T
    f32x4 sa[4] = {};
#pragma unroll
    for (int nt = 0; nt < 4; nt++) {
      if (nt * 16 <= kmax_off) {
        int kk = nt * 16 + l15;
#pragma unroll
        for (int st = 0; st < 4; st++) {
          bf16x8 kf = *(const bf16x8*)&Kls[kk * 128 + (((st * 4 + quad) ^ l15) & 15) * 8];
          sa[nt] = __builtin_amdgcn_mfma_f32_16x16x32_bf16(qf[st], kf, sa[nt], 0, 0, 0);
        }
      }
    }

    // combine + mask + row max
    float pmx[4] = {-INFINITY, -INFINITY, -INFINITY, -INFINITY};
#pragma unroll
    for (int nt = 0; nt < 4; nt++) {
      if (nt * 16 <= kmax_off) {
        int kg = k0 + nt * 16 + l15;
#pragma unroll
        for (int rg = 0; rg < 4; rg++) {
          int qg = qw0 + quad * 4 + rg;
          float v = (sa[nt][rg] + (float)srl[nt][rg]) * SCALE;
          v = (kg <= qg) ? v : -INFINITY;
          sa[nt][rg] = v;
          pmx[rg] = fmaxf(pmx[rg], v);
        }
      } else {
#pragma unroll
        for (int rg = 0; rg < 4; rg++) sa[nt][rg] = -INFINITY;
      }
    }

    // online softmax (per 16-lane row group)
#pragma unroll
    for (int rg = 0; rg < 4; rg++) {
      float v = pmx[rg];
      v = fmaxf(v, __shfl_xor(v, 1));
      v = fmaxf(v, __shfl_xor(v, 2));
      v = fmaxf(v, __shfl_xor(v, 4));
      v = fmaxf(v, __shfl_xor(v, 8));
      float mnew = fmaxf(mrow[rg], v);
      float alpha = __expf(mrow[rg] - mnew);
      mrow[rg] = mnew;
      lrow[rg] *= alpha;
#pragma unroll
      for (int nt = 0; nt < 8; nt++) o[nt][rg] *= alpha;
      pmx[rg] = mnew;
    }
    float ls[4] = {0.f, 0.f, 0.f, 0.f};
#pragma unroll
    for (int nt = 0; nt < 4; nt++)
#pragma unroll
      for (int rg = 0; rg < 4; rg++) {
        float p = __expf(sa[nt][rg] - pmx[rg]);
        ls[rg] += p;
        Pls[wave][quad * 4 + rg][nt * 16 + l15] = (bf16)p;
      }
#pragma unroll
    for (int rg = 0; rg < 4; rg++) {
      float v = ls[rg];
      v += __shfl_xor(v, 1);
      v += __shfl_xor(v, 2);
      v += __shfl_xor(v, 4);
      v += __shfl_xor(v, 8);
      lrow[rg] += v;
    }
    // Pls is per-wave: same-wave DS ordering suffices, no barrier

    // O += P @ V
    bf16x8 pf[2];
#pragma unroll
    for (int s2 = 0; s2 < 2; s2++)
      pf[s2] = *(const bf16x8*)&Pls[wave][l15][s2 * 32 + quad * 8];
#pragma unroll
    for (int nt = 0; nt < 8; nt++) {
      int d = nt * 16 + l15;
#pragma unroll
      for (int s2 = 0; s2 < 2; s2++) {
        if (s2 * 32 <= kmax_off) {
          bf16x8 vf = *(const bf16x8*)&Vls[d * 64 + (((s2 * 4 + quad) ^ (l15 & 7)) & 7) * 8];
          o[nt] = __builtin_amdgcn_mfma_f32_16x16x32_bf16(pf[s2], vf, o[nt], 0, 0, 0);
        }
      }
    }
  }

  // finalize: O / l -> y[b, q, h*128 + d] bf16
#pragma unroll
  for (int rg = 0; rg < 4; rg++) {
    float inv = 1.0f / lrow[rg];
    int qg = qw0 + quad * 4 + rg;
    bf16* yr = y + ((size_t)b * LL + qg) * DD + h * HSS;
#pragma unroll
    for (int nt = 0; nt < 8; nt++) yr[nt * 16 + l15] = (bf16)(o[nt][rg] * inv);
  }
}

// ---------------------------------------------------------------------------
extern "C" void kernel_launch(void* const* d_in, const int* in_sizes, int n_in,
                              void* d_out, int out_size, void* d_ws, size_t ws_size,
                              hipStream_t stream) {
  const float* x = (const float*)d_in[0];
  const float* W_qkv = (const float*)d_in[1];
  const float* b_qkv = (const float*)d_in[2];
  const float* W_o = (const float*)d_in[3];
  const float* b_o = (const float*)d_in[4];
  const float* Er = (const float*)d_in[5];
  const float* ln1_g = (const float*)d_in[6];
  const float* ln1_b = (const float*)d_in[7];
  const float* ln2_g = (const float*)d_in[8];
  const float* ln2_b = (const float*)d_in[9];
  const float* W_fc = (const float*)d_in[10];
  const float* b_fc = (const float*)d_in[11];
  const float* W_proj = (const float*)d_in[12];
  const float* b_proj = (const float*)d_in[13];
  float* out = (float*)d_out;

  char* p = (char*)d_ws;
  auto alloc = [&](size_t bytes) {
    char* r = p;
    p += (bytes + 255) & ~(size_t)255;
    return r;
  };
  bf16* Wt_qkv = (bf16*)alloc((size_t)3072 * 1024 * 2);
  bf16* Wt_o   = (bf16*)alloc((size_t)1024 * 1024 * 2);
  bf16* Wt_fc  = (bf16*)alloc((size_t)4096 * 1024 * 2);
  bf16* Wt_pr  = (bf16*)alloc((size_t)1024 * 4096 * 2);
  bf16* Erb    = (bf16*)alloc((size_t)1024 * 128 * 2);
  bf16* xn     = (bf16*)alloc((size_t)8192 * 1024 * 2);
  bf16* qkvb   = (bf16*)alloc((size_t)8192 * 3072 * 2);  // + yb = hb region
  bf16* yb     = (bf16*)alloc((size_t)8192 * 1024 * 2);  // must follow qkvb
  bf16* Kpack  = (bf16*)alloc((size_t)64 * 16 * 64 * 128 * 2);
  bf16* Vpack  = (bf16*)alloc((size_t)64 * 16 * 128 * 64 * 2);
  f16*  band   = (f16*)alloc((size_t)64 * 136 * 4096 * 2);  // 71.3 MB
  float* x2    = (float*)band;  // alias: band dead before x2 is written
  bf16* hb     = qkvb;          // spans qkvb+yb (66MB >= 64MB needed)

  // weight prep
  transpose_cast_kernel<<<dim3(3072 / 32, 1024 / 32), dim3(32, 8), 0, stream>>>(W_qkv, Wt_qkv, 1024, 3072);
  transpose_cast_kernel<<<dim3(1024 / 32, 1024 / 32), dim3(32, 8), 0, stream>>>(W_o, Wt_o, 1024, 1024);
  transpose_cast_kernel<<<dim3(4096 / 32, 1024 / 32), dim3(32, 8), 0, stream>>>(W_fc, Wt_fc, 1024, 4096);
  transpose_cast_kernel<<<dim3(1024 / 32, 4096 / 32), dim3(32, 8), 0, stream>>>(W_proj, Wt_pr, 4096, 1024);
  cast_bf16_kernel<<<512, 256, 0, stream>>>(Er, Erb, 1024 * 128);

  // block
  ln_kernel<<<8192, 256, 0, stream>>>(x, ln1_g, ln1_b, xn);
  gemm_kernel<0><<<dim3(24, 64), 256, 0, stream>>>(xn, Wt_qkv, b_qkv, nullptr, qkvb, 8192, 3072, 1024);
  pack_kv_kernel<<<dim3(16, 8, 8), 256, 0, stream>>>(qkvb, Kpack, Vpack);
  relband_kernel<<<dim3(16, 8, 8), 256, 0, stream>>>(qkvb, Erb, band);
  flash_kernel<<<dim3(16, 8, 8), 256, 0, stream>>>(qkvb, Kpack, Vpack, band, yb);
  gemm_kernel<2><<<dim3(8, 64), 256, 0, stream>>>(yb, Wt_o, b_o, x, x2, 8192, 1024, 1024);
  ln_kernel<<<8192, 256, 0, stream>>>(x2, ln2_g, ln2_b, xn);
  gemm_kernel<1><<<dim3(32, 64), 256, 0, stream>>>(xn, Wt_fc, b_fc, nullptr, hb, 8192, 4096, 1024);
  gemm_kernel<2><<<dim3(8, 64), 256, 0, stream>>>(hb, Wt_pr, b_proj, x2, out, 8192, 1024, 4096);
}

// Round 6
// 730.289 us; speedup vs baseline: 1.3165x; 1.0806x over previous
//
#include <hip/hip_runtime.h>
#include <hip/hip_bf16.h>
#include <math.h>

// Problem constants
#define BB 8
#define LL 1024
#define DD 1024
#define FF 4096
#define NHH 8
#define HSS 128
#define SCALE 0.08838834764831845f  // 1/sqrt(128)
#define TRI(qi, kt) ((qi) * ((qi) + 1) / 2 + (kt))

typedef __bf16 bf16;
typedef __bf16 bf16x8 __attribute__((ext_vector_type(8)));
typedef float f32x4 __attribute__((ext_vector_type(4)));
typedef _Float16 f16;
typedef _Float16 f16x4 __attribute__((ext_vector_type(4)));

__device__ inline void async_copy16(const void* g, void* l) {
  __builtin_amdgcn_global_load_lds(
      (const __attribute__((address_space(1))) unsigned int*)g,
      (__attribute__((address_space(3))) unsigned int*)l, 16, 0, 0);
}

// ---------------------------------------------------------------------------
// Transpose + cast: W [K][N] fp32 -> Wt [N][K] bf16
// ---------------------------------------------------------------------------
__global__ __launch_bounds__(256)
void transpose_cast_kernel(const float* __restrict__ W, bf16* __restrict__ Wt,
                           int K, int N) {
  __shared__ float tile[32][33];
  int n0 = blockIdx.x * 32, k0 = blockIdx.y * 32;
  int tx = threadIdx.x, ty = threadIdx.y;
#pragma unroll
  for (int i = 0; i < 32; i += 8)
    tile[ty + i][tx] = W[(size_t)(k0 + ty + i) * N + n0 + tx];
  __syncthreads();
#pragma unroll
  for (int i = 0; i < 32; i += 8)
    Wt[(size_t)(n0 + ty + i) * K + k0 + tx] = (bf16)tile[tx][ty + i];
}

__global__ __launch_bounds__(256)
void cast_bf16_kernel(const float* __restrict__ src, bf16* __restrict__ dst, int n) {
  int i = blockIdx.x * blockDim.x + threadIdx.x;
  if (i < n) dst[i] = (bf16)src[i];
}

// ---------------------------------------------------------------------------
// LayerNorm: x [8192][1024] fp32 -> out bf16
// ---------------------------------------------------------------------------
__global__ __launch_bounds__(256)
void ln_kernel(const float* __restrict__ x, const float* __restrict__ g,
               const float* __restrict__ bta, bf16* __restrict__ out) {
  int row = blockIdx.x;
  int tid = threadIdx.x;
  const float4 v = ((const float4*)(x + (size_t)row * DD))[tid];
  float s = v.x + v.y + v.z + v.w;
  float s2 = v.x * v.x + v.y * v.y + v.z * v.z + v.w * v.w;
#pragma unroll
  for (int o = 32; o > 0; o >>= 1) {
    s += __shfl_down(s, o);
    s2 += __shfl_down(s2, o);
  }
  __shared__ float a1[4], a2[4];
  int wave = tid >> 6;
  if ((tid & 63) == 0) { a1[wave] = s; a2[wave] = s2; }
  __syncthreads();
  s = a1[0] + a1[1] + a1[2] + a1[3];
  s2 = a2[0] + a2[1] + a2[2] + a2[3];
  float mu = s * (1.0f / DD);
  float rstd = rsqrtf(s2 * (1.0f / DD) - mu * mu + 1e-5f);
  float4 gv = ((const float4*)g)[tid];
  float4 bv = ((const float4*)bta)[tid];
  bf16* o4 = out + (size_t)row * DD + tid * 4;
  o4[0] = (bf16)((v.x - mu) * rstd * gv.x + bv.x);
  o4[1] = (bf16)((v.y - mu) * rstd * gv.y + bv.y);
  o4[2] = (bf16)((v.z - mu) * rstd * gv.z + bv.z);
  o4[3] = (bf16)((v.w - mu) * rstd * gv.w + bv.w);
}

// ---------------------------------------------------------------------------
// GEMM: C[M][N] = A[M][K](bf16) * Bt[N][K](bf16)^T + bias
// EPI 0: -> bf16   EPI 1: gelu -> bf16   EPI 2: + res(fp32) -> fp32
// ---------------------------------------------------------------------------
template <int EPI>
__global__ __launch_bounds__(256)
void gemm_kernel(const bf16* __restrict__ A, const bf16* __restrict__ Bt,
                 const float* __restrict__ bias, const float* __restrict__ res,
                 void* __restrict__ Cout, int M, int N, int K) {
  __shared__ bf16 Als[128 * 32];
  __shared__ bf16 Bls[128 * 32];
  int tid = threadIdx.x;
  int wave = tid >> 6, lane = tid & 63;
  int l15 = lane & 15, quad = lane >> 4;
  int m0 = blockIdx.y * 128, n0 = blockIdx.x * 128;
  int wm = (wave >> 1) * 64, wn = (wave & 1) * 64;
  f32x4 acc[4][4] = {};

  for (int k0 = 0; k0 < K; k0 += 32) {
    __syncthreads();
#pragma unroll
    for (int i = 0; i < 2; i++) {
      int t = i * 256 + tid;
      int row = t >> 2, kc = (t & 3) << 3;
      async_copy16(A + (size_t)(m0 + row) * K + k0 + kc, &Als[t * 8]);
      async_copy16(Bt + (size_t)(n0 + row) * K + k0 + kc, &Bls[t * 8]);
    }
    __syncthreads();
    bf16x8 af[4], bfr[4];
#pragma unroll
    for (int mt = 0; mt < 4; mt++)
      af[mt] = *(const bf16x8*)&Als[(wm + mt * 16 + l15) * 32 + quad * 8];
#pragma unroll
    for (int nt = 0; nt < 4; nt++)
      bfr[nt] = *(const bf16x8*)&Bls[(wn + nt * 16 + l15) * 32 + quad * 8];
#pragma unroll
    for (int mt = 0; mt < 4; mt++)
#pragma unroll
      for (int nt = 0; nt < 4; nt++)
        acc[mt][nt] = __builtin_amdgcn_mfma_f32_16x16x32_bf16(af[mt], bfr[nt],
                                                              acc[mt][nt], 0, 0, 0);
  }

#pragma unroll
  for (int mt = 0; mt < 4; mt++) {
#pragma unroll
    for (int nt = 0; nt < 4; nt++) {
      int col = n0 + wn + nt * 16 + l15;
      float bv = bias[col];
#pragma unroll
      for (int r = 0; r < 4; r++) {
        int row = m0 + wm + mt * 16 + quad * 4 + r;
        float v = acc[mt][nt][r] + bv;
        if (EPI == 1) v = 0.5f * v * (1.0f + erff(v * 0.7071067811865475f));
        if (EPI == 2) {
          v += res[(size_t)row * N + col];
          ((float*)Cout)[(size_t)row * N + col] = v;
        } else {
          ((bf16*)Cout)[(size_t)row * N + col] = (bf16)v;
        }
      }
    }
  }
}

// ---------------------------------------------------------------------------
// pack_kv: per (b,h,kt) repack K into [kk][chunk^swizzle] and V transposed
// into [d][chunk^swizzle], 16B chunks, so flash can DMA-stage with
// global_load_lds and read fragments conflict-free.
// ---------------------------------------------------------------------------
__global__ __launch_bounds__(256)
void pack_kv_kernel(const bf16* __restrict__ qkv, bf16* __restrict__ Kpack,
                    bf16* __restrict__ Vpack) {
  __shared__ bf16 Vst[64][132];  // raw V tile [kk][d], padded
  int kt = blockIdx.x, h = blockIdx.y, b = blockIdx.z;
  int tid = threadIdx.x;
  const size_t rs = 3 * DD;
  const bf16* kb = qkv + (size_t)b * LL * rs + (size_t)(kt * 64) * rs + DD + h * HSS;
  const bf16* vb = kb + DD;
  bf16* kp = Kpack + ((size_t)(b * NHH + h) * 16 + kt) * (64 * 128);
  bf16* vp = Vpack + ((size_t)(b * NHH + h) * 16 + kt) * (128 * 64);
#pragma unroll
  for (int i = 0; i < 4; i++) {
    int u = i * 256 + tid;
    int kk = u >> 4, c = u & 15;
    // K: element (kk,d): chunk c=d>>3 stored at (c ^ (kk&15))
    bf16x8 kv = *(const bf16x8*)(kb + (size_t)kk * rs + c * 8);
    *(bf16x8*)(kp + kk * 128 + ((c ^ kk) & 15) * 8) = kv;
    // V raw stage for transpose
    *(bf16x8*)&Vst[kk][c * 8] = *(const bf16x8*)(vb + (size_t)kk * rs + c * 8);
  }
  __syncthreads();
#pragma unroll
  for (int i = 0; i < 4; i++) {
    int u = i * 256 + tid;
    int d = u >> 3, c = u & 7;  // V^T row d, kk-chunk c (kk = c*8+j)
    bf16x8 t;
#pragma unroll
    for (int j = 0; j < 8; j++) t[j] = Vst[c * 8 + j][d];
    *(bf16x8*)(vp + d * 64 + ((c ^ (d & 7))) * 8) = t;
  }
}

// ---------------------------------------------------------------------------
// relband v3: TILE-PARALLEL. One block per 64x64 band tile (8704 blocks,
// uniform work) instead of one block per qi-row-strip walking <=16 tiles.
// Body identical math to v2: R = Q@Er^T in C-layout, in-register bpermute
// diagonal gather, fragment-layout coalesced f16x4 stores.
// ---------------------------------------------------------------------------
__global__ __launch_bounds__(256)
void relband_kernel(const bf16* __restrict__ qkv, const bf16* __restrict__ Erb,
                    f16* __restrict__ band) {
  int t = blockIdx.x;  // triangular tile index 0..135
  int h = blockIdx.y, b = blockIdx.z;
  // decode (qi, kt): qi = row of triangle, kt = col
  int qi = (int)((sqrtf((float)(8 * t + 1)) - 1.0f) * 0.5f);
  while (TRI(qi + 1, 0) <= t) qi++;
  while (TRI(qi, 0) > t) qi--;
  int kt = t - TRI(qi, 0);

  int tid = threadIdx.x, wave = tid >> 6, lane = tid & 63;
  int l15 = lane & 15, quad = lane >> 4;
  int qw0 = qi * 64 + wave * 16;
  int k0 = kt * 64;
  const size_t rs = 3 * DD;
  const bf16* qbase = qkv + (size_t)b * LL * rs + h * HSS;
  bf16x8 qf[4];
#pragma unroll
  for (int st = 0; st < 4; st++)
    qf[st] = *(const bf16x8*)(qbase + (size_t)(qw0 + l15) * rs + st * 32 + quad * 8);

  int kmax_off = qw0 + 15 - k0;  // wave-uniform, >= 15
  int m_base = 1008 - qw0 + k0;
  int ntR = (kmax_off >> 4) + 1;
  if (ntR > 4) ntR = 4;
  // R tiles in C-layout: rr[n][rg] = R[q=qw0+quad*4+rg][m=m_base+n*16+l15]
  f32x4 rr[5] = {};
#pragma unroll
  for (int n = 0; n < 5; n++) {
    if (n <= ntR) {
      int mr = m_base + n * 16 + l15;
      mr = mr < 0 ? 0 : (mr > 1023 ? 1023 : mr);
#pragma unroll
      for (int st = 0; st < 4; st++) {
        bf16x8 ef = *(const bf16x8*)(Erb + (size_t)mr * HSS + st * 32 + quad * 8);
        rr[n] = __builtin_amdgcn_mfma_f32_16x16x32_bf16(qf[st], ef, rr[n], 0, 0, 0);
      }
    }
  }
  // diagonal gather: Srel[q][k] = R[q][m], m = 1023-q+k  (c = 15-qloc+koff)
  f16x4 sf[4];
#pragma unroll
  for (int rg = 0; rg < 4; rg++) {
    int qloc = quad * 4 + rg;
    int tt = 15 - qloc + l15;           // 0..30
    int src = (lane & 48) | (tt & 15);  // same quad-row, rotated col
    float shv[5];
#pragma unroll
    for (int n = 0; n < 5; n++)
      shv[n] = (n <= ntR) ? __shfl(rr[n][rg], src) : 0.f;
#pragma unroll
    for (int nt = 0; nt < 4; nt++)
      sf[nt][rg] = (f16)((tt & 16) ? shv[nt + 1] : shv[nt]);
  }
  // coalesced fragment store (512B per wave store)
  f16* tb = band + (size_t)(b * NHH + h) * (136 * 4096) + (size_t)t * 4096;
#pragma unroll
  for (int nt = 0; nt < 4; nt++)
    if (nt * 16 <= kmax_off)
      *(f16x4*)(tb + (wave * 4 + nt) * 256 + l15 * 16 + quad * 4) = sf[nt];
}

// ---------------------------------------------------------------------------
// Flash attention v5: DMA-staged swizzled K/V tiles, fragment-layout Srel
// band (coalesced f16x4 loads). Block: 4 waves, BQ=64, BK=64.
// ---------------------------------------------------------------------------
__global__ __launch_bounds__(256)
void flash_kernel(const bf16* __restrict__ qkv, const bf16* __restrict__ Kpack,
                  const bf16* __restrict__ Vpack, const f16* __restrict__ band,
                  bf16* __restrict__ y) {
  __shared__ bf16 Kls[64 * 128];  // [kk][chunk^kk swizzle]
  __shared__ bf16 Vls[128 * 64];  // [d][chunk^d swizzle]
  __shared__ bf16 Pls[4][16][72];

  int tid = threadIdx.x, wave = tid >> 6, lane = tid & 63;
  int l15 = lane & 15, quad = lane >> 4;
  int qb = 15 - blockIdx.x;  // LPT
  int h = blockIdx.y, b = blockIdx.z;
  int qw0 = qb * 64 + wave * 16;

  const size_t rs = 3 * DD;
  const bf16* qbase = qkv + (size_t)b * LL * rs + h * HSS;
  const bf16* kp = Kpack + (size_t)(b * NHH + h) * 16 * (64 * 128);
  const bf16* vp = Vpack + (size_t)(b * NHH + h) * 16 * (128 * 64);
  const f16* bnd = band + (size_t)(b * NHH + h) * (136 * 4096);

  bf16x8 qf[4];
#pragma unroll
  for (int st = 0; st < 4; st++)
    qf[st] = *(const bf16x8*)(qbase + (size_t)(qw0 + l15) * rs + st * 32 + quad * 8);

  f32x4 o[8] = {};
  float mrow[4] = {-INFINITY, -INFINITY, -INFINITY, -INFINITY};
  float lrow[4] = {0.f, 0.f, 0.f, 0.f};

  int nkt = qb + 1;
  for (int kt = 0; kt < nkt; kt++) {
    int k0 = kt * 64;
    int kmax_off = qw0 + 15 - k0;  // wave-uniform
    __syncthreads();  // prev tile's LDS readers done
    // DMA stage K (16KB) + V^T (16KB); per wave 4+4 instrs, lane-linear
    {
      const bf16* ks = kp + (size_t)kt * (64 * 128);
      const bf16* vs = vp + (size_t)kt * (128 * 64);
#pragma unroll
      for (int i = 0; i < 4; i++) {
        int off = (wave * 4 + i) * 512 + lane * 8;
        async_copy16(ks + off, &Kls[off]);
        async_copy16(vs + off, &Vls[off]);
      }
    }
    // Srel band fragments, C-layout match, 512B/wave coalesced (L2/L3-hot)
    const f16* tb = bnd + (size_t)TRI(qb, kt) * 4096;
    f16x4 srl[4] = {};
#pragma unroll
    for (int nt = 0; nt < 4; nt++)
      if (nt * 16 <= kmax_off)
        srl[nt] = *(const f16x4*)(tb + (wave * 4 + nt) * 256 + l15 * 16 + quad * 4);
    __syncthreads();  // drains DMA (vmcnt0) once per tile

    // S = Q K^T
    f32x4 sa[4] = {};
#pragma unroll
    for (int nt = 0; nt < 4; nt++) {
      if (nt * 16 <= kmax_off) {
        int kk = nt * 16 + l15;
#pragma unroll
        for (int st = 0; st < 4; st++) {
          bf16x8 kf = *(const bf16x8*)&Kls[kk * 128 + (((st * 4 + quad) ^ l15) & 15) * 8];
          sa[nt] = __builtin_amdgcn_mfma_f32_16x16x32_bf16(qf[st], kf, sa[nt], 0, 0, 0);
        }
      }
    }

    // combine + mask + row max
    float pmx[4] = {-INFINITY, -INFINITY, -INFINITY, -INFINITY};
#pragma unroll
    for (int nt = 0; nt < 4; nt++) {
      if (nt * 16 <= kmax_off) {
        int kg = k0 + nt * 16 + l15;
#pragma unroll
        for (int rg = 0; rg < 4; rg++) {
          int qg = qw0 + quad * 4 + rg;
          float v = (sa[nt][rg] + (float)srl[nt][rg]) * SCALE;
          v = (kg <= qg) ? v : -INFINITY;
          sa[nt][rg] = v;
          pmx[rg] = fmaxf(pmx[rg], v);
        }
      } else {
#pragma unroll
        for (int rg = 0; rg < 4; rg++) sa[nt][rg] = -INFINITY;
      }
    }

    // online softmax (per 16-lane row group)
#pragma unroll
    for (int rg = 0; rg < 4; rg++) {
      float v = pmx[rg];
      v = fmaxf(v, __shfl_xor(v, 1));
      v = fmaxf(v, __shfl_xor(v, 2));
      v = fmaxf(v, __shfl_xor(v, 4));
      v = fmaxf(v, __shfl_xor(v, 8));
      float mnew = fmaxf(mrow[rg], v);
      float alpha = __expf(mrow[rg] - mnew);
      mrow[rg] = mnew;
      lrow[rg] *= alpha;
#pragma unroll
      for (int nt = 0; nt < 8; nt++) o[nt][rg] *= alpha;
      pmx[rg] = mnew;
    }
    float ls[4] = {0.f, 0.f, 0.f, 0.f};
#pragma unroll
    for (int nt = 0; nt < 4; nt++)
#pragma unroll
      for (int rg = 0; rg < 4; rg++) {
        float p = __expf(sa[nt][rg] - pmx[rg]);
        ls[rg] += p;
        Pls[wave][quad * 4 + rg][nt * 16 + l15] = (bf16)p;
      }
#pragma unroll
    for (int rg = 0; rg < 4; rg++) {
      float v = ls[rg];
      v += __shfl_xor(v, 1);
      v += __shfl_xor(v, 2);
      v += __shfl_xor(v, 4);
      v += __shfl_xor(v, 8);
      lrow[rg] += v;
    }
    // Pls is per-wave: same-wave DS ordering suffices, no barrier

    // O += P @ V
    bf16x8 pf[2];
#pragma unroll
    for (int s2 = 0; s2 < 2; s2++)
      pf[s2] = *(const bf16x8*)&Pls[wave][l15][s2 * 32 + quad * 8];
#pragma unroll
    for (int nt = 0; nt < 8; nt++) {
      int d = nt * 16 + l15;
#pragma unroll
      for (int s2 = 0; s2 < 2; s2++) {
        if (s2 * 32 <= kmax_off) {
          bf16x8 vf = *(const bf16x8*)&Vls[d * 64 + (((s2 * 4 + quad) ^ (l15 & 7)) & 7) * 8];
          o[nt] = __builtin_amdgcn_mfma_f32_16x16x32_bf16(pf[s2], vf, o[nt], 0, 0, 0);
        }
      }
    }
  }

  // finalize: O / l -> y[b, q, h*128 + d] bf16
#pragma unroll
  for (int rg = 0; rg < 4; rg++) {
    float inv = 1.0f / lrow[rg];
    int qg = qw0 + quad * 4 + rg;
    bf16* yr = y + ((size_t)b * LL + qg) * DD + h * HSS;
#pragma unroll
    for (int nt = 0; nt < 8; nt++) yr[nt * 16 + l15] = (bf16)(o[nt][rg] * inv);
  }
}

// ---------------------------------------------------------------------------
extern "C" void kernel_launch(void* const* d_in, const int* in_sizes, int n_in,
                              void* d_out, int out_size, void* d_ws, size_t ws_size,
                              hipStream_t stream) {
  const float* x = (const float*)d_in[0];
  const float* W_qkv = (const float*)d_in[1];
  const float* b_qkv = (const float*)d_in[2];
  const float* W_o = (const float*)d_in[3];
  const float* b_o = (const float*)d_in[4];
  const float* Er = (const float*)d_in[5];
  const float* ln1_g = (const float*)d_in[6];
  const float* ln1_b = (const float*)d_in[7];
  const float* ln2_g = (const float*)d_in[8];
  const float* ln2_b = (const float*)d_in[9];
  const float* W_fc = (const float*)d_in[10];
  const float* b_fc = (const float*)d_in[11];
  const float* W_proj = (const float*)d_in[12];
  const float* b_proj = (const float*)d_in[13];
  float* out = (float*)d_out;

  char* p = (char*)d_ws;
  auto alloc = [&](size_t bytes) {
    char* r = p;
    p += (bytes + 255) & ~(size_t)255;
    return r;
  };
  bf16* Wt_qkv = (bf16*)alloc((size_t)3072 * 1024 * 2);
  bf16* Wt_o   = (bf16*)alloc((size_t)1024 * 1024 * 2);
  bf16* Wt_fc  = (bf16*)alloc((size_t)4096 * 1024 * 2);
  bf16* Wt_pr  = (bf16*)alloc((size_t)1024 * 4096 * 2);
  bf16* Erb    = (bf16*)alloc((size_t)1024 * 128 * 2);
  bf16* xn     = (bf16*)alloc((size_t)8192 * 1024 * 2);
  bf16* qkvb   = (bf16*)alloc((size_t)8192 * 3072 * 2);  // + yb = hb region
  bf16* yb     = (bf16*)alloc((size_t)8192 * 1024 * 2);  // must follow qkvb
  bf16* Kpack  = (bf16*)alloc((size_t)64 * 16 * 64 * 128 * 2);
  bf16* Vpack  = (bf16*)alloc((size_t)64 * 16 * 128 * 64 * 2);
  f16*  band   = (f16*)alloc((size_t)64 * 136 * 4096 * 2);  // 71.3 MB
  float* x2    = (float*)band;  // alias: band dead before x2 is written
  bf16* hb     = qkvb;          // spans qkvb+yb (66MB >= 64MB needed)

  // weight prep
  transpose_cast_kernel<<<dim3(3072 / 32, 1024 / 32), dim3(32, 8), 0, stream>>>(W_qkv, Wt_qkv, 1024, 3072);
  transpose_cast_kernel<<<dim3(1024 / 32, 1024 / 32), dim3(32, 8), 0, stream>>>(W_o, Wt_o, 1024, 1024);
  transpose_cast_kernel<<<dim3(4096 / 32, 1024 / 32), dim3(32, 8), 0, stream>>>(W_fc, Wt_fc, 1024, 4096);
  transpose_cast_kernel<<<dim3(1024 / 32, 4096 / 32), dim3(32, 8), 0, stream>>>(W_proj, Wt_pr, 4096, 1024);
  cast_bf16_kernel<<<512, 256, 0, stream>>>(Er, Erb, 1024 * 128);

  // block
  ln_kernel<<<8192, 256, 0, stream>>>(x, ln1_g, ln1_b, xn);
  gemm_kernel<0><<<dim3(24, 64), 256, 0, stream>>>(xn, Wt_qkv, b_qkv, nullptr, qkvb, 8192, 3072, 1024);
  pack_kv_kernel<<<dim3(16, 8, 8), 256, 0, stream>>>(qkvb, Kpack, Vpack);
  relband_kernel<<<dim3(136, 8, 8), 256, 0, stream>>>(qkvb, Erb, band);
  flash_kernel<<<dim3(16, 8, 8), 256, 0, stream>>>(qkvb, Kpack, Vpack, band, yb);
  gemm_kernel<2><<<dim3(8, 64), 256, 0, stream>>>(yb, Wt_o, b_o, x, x2, 8192, 1024, 1024);
  ln_kernel<<<8192, 256, 0, stream>>>(x2, ln2_g, ln2_b, xn);
  gemm_kernel<1><<<dim3(32, 64), 256, 0, stream>>>(xn, Wt_fc, b_fc, nullptr, hb, 8192, 4096, 1024);
  gemm_kernel<2><<<dim3(8, 64), 256, 0, stream>>>(hb, Wt_pr, b_proj, x2, out, 8192, 1024, 4096);
}

// Round 7
// 691.018 us; speedup vs baseline: 1.3914x; 1.0568x over previous
//
#include <hip/hip_runtime.h>
#include <hip/hip_bf16.h>
#include <math.h>

// Problem constants
#define BB 8
#define LL 1024
#define DD 1024
#define FF 4096
#define NHH 8
#define HSS 128
#define SCALE 0.08838834764831845f  // 1/sqrt(128)
#define TRI(qi, kt) ((qi) * ((qi) + 1) / 2 + (kt))

typedef __bf16 bf16;
typedef __bf16 bf16x8 __attribute__((ext_vector_type(8)));
typedef float f32x4 __attribute__((ext_vector_type(4)));
typedef _Float16 f16;
typedef _Float16 f16x4 __attribute__((ext_vector_type(4)));

__device__ inline void async_copy16(const void* g, void* l) {
  __builtin_amdgcn_global_load_lds(
      (const __attribute__((address_space(1))) unsigned int*)g,
      (__attribute__((address_space(3))) unsigned int*)l, 16, 0, 0);
}

// ---------------------------------------------------------------------------
// Transpose + cast: W [K][N] fp32 -> Wt [N][K] bf16
// ---------------------------------------------------------------------------
__global__ __launch_bounds__(256)
void transpose_cast_kernel(const float* __restrict__ W, bf16* __restrict__ Wt,
                           int K, int N) {
  __shared__ float tile[32][33];
  int n0 = blockIdx.x * 32, k0 = blockIdx.y * 32;
  int tx = threadIdx.x, ty = threadIdx.y;
#pragma unroll
  for (int i = 0; i < 32; i += 8)
    tile[ty + i][tx] = W[(size_t)(k0 + ty + i) * N + n0 + tx];
  __syncthreads();
#pragma unroll
  for (int i = 0; i < 32; i += 8)
    Wt[(size_t)(n0 + ty + i) * K + k0 + tx] = (bf16)tile[tx][ty + i];
}

__global__ __launch_bounds__(256)
void cast_bf16_kernel(const float* __restrict__ src, bf16* __restrict__ dst, int n) {
  int i = blockIdx.x * blockDim.x + threadIdx.x;
  if (i < n) dst[i] = (bf16)src[i];
}

// ---------------------------------------------------------------------------
// LayerNorm: x [8192][1024] fp32 -> out bf16
// ---------------------------------------------------------------------------
__global__ __launch_bounds__(256)
void ln_kernel(const float* __restrict__ x, const float* __restrict__ g,
               const float* __restrict__ bta, bf16* __restrict__ out) {
  int row = blockIdx.x;
  int tid = threadIdx.x;
  const float4 v = ((const float4*)(x + (size_t)row * DD))[tid];
  float s = v.x + v.y + v.z + v.w;
  float s2 = v.x * v.x + v.y * v.y + v.z * v.z + v.w * v.w;
#pragma unroll
  for (int o = 32; o > 0; o >>= 1) {
    s += __shfl_down(s, o);
    s2 += __shfl_down(s2, o);
  }
  __shared__ float a1[4], a2[4];
  int wave = tid >> 6;
  if ((tid & 63) == 0) { a1[wave] = s; a2[wave] = s2; }
  __syncthreads();
  s = a1[0] + a1[1] + a1[2] + a1[3];
  s2 = a2[0] + a2[1] + a2[2] + a2[3];
  float mu = s * (1.0f / DD);
  float rstd = rsqrtf(s2 * (1.0f / DD) - mu * mu + 1e-5f);
  float4 gv = ((const float4*)g)[tid];
  float4 bv = ((const float4*)bta)[tid];
  bf16* o4 = out + (size_t)row * DD + tid * 4;
  o4[0] = (bf16)((v.x - mu) * rstd * gv.x + bv.x);
  o4[1] = (bf16)((v.y - mu) * rstd * gv.y + bv.y);
  o4[2] = (bf16)((v.z - mu) * rstd * gv.z + bv.z);
  o4[3] = (bf16)((v.w - mu) * rstd * gv.w + bv.w);
}

// ---------------------------------------------------------------------------
// GEMM: C[M][N] = A[M][K](bf16) * Bt[N][K](bf16)^T + bias
// EPI 0: -> bf16   EPI 1: gelu -> bf16   EPI 2: + res(fp32) -> fp32
// ---------------------------------------------------------------------------
template <int EPI>
__global__ __launch_bounds__(256)
void gemm_kernel(const bf16* __restrict__ A, const bf16* __restrict__ Bt,
                 const float* __restrict__ bias, const float* __restrict__ res,
                 void* __restrict__ Cout, int M, int N, int K) {
  __shared__ bf16 Als[128 * 32];
  __shared__ bf16 Bls[128 * 32];
  int tid = threadIdx.x;
  int wave = tid >> 6, lane = tid & 63;
  int l15 = lane & 15, quad = lane >> 4;
  int m0 = blockIdx.y * 128, n0 = blockIdx.x * 128;
  int wm = (wave >> 1) * 64, wn = (wave & 1) * 64;
  f32x4 acc[4][4] = {};

  for (int k0 = 0; k0 < K; k0 += 32) {
    __syncthreads();
#pragma unroll
    for (int i = 0; i < 2; i++) {
      int t = i * 256 + tid;
      int row = t >> 2, kc = (t & 3) << 3;
      async_copy16(A + (size_t)(m0 + row) * K + k0 + kc, &Als[t * 8]);
      async_copy16(Bt + (size_t)(n0 + row) * K + k0 + kc, &Bls[t * 8]);
    }
    __syncthreads();
    bf16x8 af[4], bfr[4];
#pragma unroll
    for (int mt = 0; mt < 4; mt++)
      af[mt] = *(const bf16x8*)&Als[(wm + mt * 16 + l15) * 32 + quad * 8];
#pragma unroll
    for (int nt = 0; nt < 4; nt++)
      bfr[nt] = *(const bf16x8*)&Bls[(wn + nt * 16 + l15) * 32 + quad * 8];
#pragma unroll
    for (int mt = 0; mt < 4; mt++)
#pragma unroll
      for (int nt = 0; nt < 4; nt++)
        acc[mt][nt] = __builtin_amdgcn_mfma_f32_16x16x32_bf16(af[mt], bfr[nt],
                                                              acc[mt][nt], 0, 0, 0);
  }

#pragma unroll
  for (int mt = 0; mt < 4; mt++) {
#pragma unroll
    for (int nt = 0; nt < 4; nt++) {
      int col = n0 + wn + nt * 16 + l15;
      float bv = bias[col];
#pragma unroll
      for (int r = 0; r < 4; r++) {
        int row = m0 + wm + mt * 16 + quad * 4 + r;
        float v = acc[mt][nt][r] + bv;
        if (EPI == 1) v = 0.5f * v * (1.0f + erff(v * 0.7071067811865475f));
        if (EPI == 2) {
          v += res[(size_t)row * N + col];
          ((float*)Cout)[(size_t)row * N + col] = v;
        } else {
          ((bf16*)Cout)[(size_t)row * N + col] = (bf16)v;
        }
      }
    }
  }
}

// ---------------------------------------------------------------------------
// pack_kv: per (b,h,kt) repack K into [kk][chunk^swizzle] and V transposed
// into [d][chunk^swizzle], 16B chunks, so flash can DMA-stage with
// global_load_lds and read fragments conflict-free.
// ---------------------------------------------------------------------------
__global__ __launch_bounds__(256)
void pack_kv_kernel(const bf16* __restrict__ qkv, bf16* __restrict__ Kpack,
                    bf16* __restrict__ Vpack) {
  __shared__ bf16 Vst[64][132];  // raw V tile [kk][d], padded
  int kt = blockIdx.x, h = blockIdx.y, b = blockIdx.z;
  int tid = threadIdx.x;
  const size_t rs = 3 * DD;
  const bf16* kb = qkv + (size_t)b * LL * rs + (size_t)(kt * 64) * rs + DD + h * HSS;
  const bf16* vb = kb + DD;
  bf16* kp = Kpack + ((size_t)(b * NHH + h) * 16 + kt) * (64 * 128);
  bf16* vp = Vpack + ((size_t)(b * NHH + h) * 16 + kt) * (128 * 64);
#pragma unroll
  for (int i = 0; i < 4; i++) {
    int u = i * 256 + tid;
    int kk = u >> 4, c = u & 15;
    // K: element (kk,d): chunk c=d>>3 stored at (c ^ (kk&15))
    bf16x8 kv = *(const bf16x8*)(kb + (size_t)kk * rs + c * 8);
    *(bf16x8*)(kp + kk * 128 + ((c ^ kk) & 15) * 8) = kv;
    // V raw stage for transpose
    *(bf16x8*)&Vst[kk][c * 8] = *(const bf16x8*)(vb + (size_t)kk * rs + c * 8);
  }
  __syncthreads();
#pragma unroll
  for (int i = 0; i < 4; i++) {
    int u = i * 256 + tid;
    int d = u >> 3, c = u & 7;  // V^T row d, kk-chunk c (kk = c*8+j)
    bf16x8 t;
#pragma unroll
    for (int j = 0; j < 8; j++) t[j] = Vst[c * 8 + j][d];
    *(bf16x8*)(vp + d * 64 + ((c ^ (d & 7))) * 8) = t;
  }
}

// ---------------------------------------------------------------------------
// relband v3: TILE-PARALLEL. One block per 64x64 band tile (8704 blocks,
// uniform work). R = Q@Er^T in C-layout, in-register bpermute diagonal
// gather, fragment-layout coalesced f16x4 stores.
// ---------------------------------------------------------------------------
__global__ __launch_bounds__(256)
void relband_kernel(const bf16* __restrict__ qkv, const bf16* __restrict__ Erb,
                    f16* __restrict__ band) {
  int t = blockIdx.x;  // triangular tile index 0..135
  int h = blockIdx.y, b = blockIdx.z;
  // decode (qi, kt): qi = row of triangle, kt = col
  int qi = (int)((sqrtf((float)(8 * t + 1)) - 1.0f) * 0.5f);
  while (TRI(qi + 1, 0) <= t) qi++;
  while (TRI(qi, 0) > t) qi--;
  int kt = t - TRI(qi, 0);

  int tid = threadIdx.x, wave = tid >> 6, lane = tid & 63;
  int l15 = lane & 15, quad = lane >> 4;
  int qw0 = qi * 64 + wave * 16;
  int k0 = kt * 64;
  const size_t rs = 3 * DD;
  const bf16* qbase = qkv + (size_t)b * LL * rs + h * HSS;
  bf16x8 qf[4];
#pragma unroll
  for (int st = 0; st < 4; st++)
    qf[st] = *(const bf16x8*)(qbase + (size_t)(qw0 + l15) * rs + st * 32 + quad * 8);

  int kmax_off = qw0 + 15 - k0;  // wave-uniform, >= 15
  int m_base = 1008 - qw0 + k0;
  int ntR = (kmax_off >> 4) + 1;
  if (ntR > 4) ntR = 4;
  // R tiles in C-layout: rr[n][rg] = R[q=qw0+quad*4+rg][m=m_base+n*16+l15]
  f32x4 rr[5] = {};
#pragma unroll
  for (int n = 0; n < 5; n++) {
    if (n <= ntR) {
      int mr = m_base + n * 16 + l15;
      mr = mr < 0 ? 0 : (mr > 1023 ? 1023 : mr);
#pragma unroll
      for (int st = 0; st < 4; st++) {
        bf16x8 ef = *(const bf16x8*)(Erb + (size_t)mr * HSS + st * 32 + quad * 8);
        rr[n] = __builtin_amdgcn_mfma_f32_16x16x32_bf16(qf[st], ef, rr[n], 0, 0, 0);
      }
    }
  }
  // diagonal gather: Srel[q][k] = R[q][m], m = 1023-q+k  (c = 15-qloc+koff)
  f16x4 sf[4];
#pragma unroll
  for (int rg = 0; rg < 4; rg++) {
    int qloc = quad * 4 + rg;
    int tt = 15 - qloc + l15;           // 0..30
    int src = (lane & 48) | (tt & 15);  // same quad-row, rotated col
    float shv[5];
#pragma unroll
    for (int n = 0; n < 5; n++)
      shv[n] = (n <= ntR) ? __shfl(rr[n][rg], src) : 0.f;
#pragma unroll
    for (int nt = 0; nt < 4; nt++)
      sf[nt][rg] = (f16)((tt & 16) ? shv[nt + 1] : shv[nt]);
  }
  // coalesced fragment store (512B per wave store)
  f16* tb = band + (size_t)(b * NHH + h) * (136 * 4096) + (size_t)t * 4096;
#pragma unroll
  for (int nt = 0; nt < 4; nt++)
    if (nt * 16 <= kmax_off)
      *(f16x4*)(tb + (wave * 4 + nt) * 256 + l15 * 16 + quad * 4) = sf[nt];
}

// ---------------------------------------------------------------------------
// Flash attention v6: balanced pairing (block does q-tiles x and 15-x -> 17
// k-tiles per block, grid 512 uniform blocks = 2/CU resident) + LDS
// double-buffered K/V DMA (prefetch kt+1 during compute of kt; one barrier
// per tile; band loads issued before DMA so their vmcnt wait doesn't drain
// the prefetch).
// ---------------------------------------------------------------------------
__global__ __launch_bounds__(256)
void flash_kernel(const bf16* __restrict__ qkv, const bf16* __restrict__ Kpack,
                  const bf16* __restrict__ Vpack, const f16* __restrict__ band,
                  bf16* __restrict__ y) {
  __shared__ bf16 Kls[2][64 * 128];  // [kk][chunk^kk swizzle], double-buffered
  __shared__ bf16 Vls[2][128 * 64];  // [d][chunk^d swizzle], double-buffered
  __shared__ bf16 Pls[4][16][72];

  int tid = threadIdx.x, wave = tid >> 6, lane = tid & 63;
  int l15 = lane & 15, quad = lane >> 4;
  int h = blockIdx.y, b = blockIdx.z;

  const size_t rs = 3 * DD;
  const bf16* qbase = qkv + (size_t)b * LL * rs + h * HSS;
  const bf16* kp = Kpack + (size_t)(b * NHH + h) * 16 * (64 * 128);
  const bf16* vp = Vpack + (size_t)(b * NHH + h) * 16 * (128 * 64);
  const f16* bnd = band + (size_t)(b * NHH + h) * (136 * 4096);

  int buf = 0;  // global tile parity across both phases
#pragma unroll 1
  for (int ph = 0; ph < 2; ph++) {
    int qb = ph ? 15 - blockIdx.x : blockIdx.x;
    int qw0 = qb * 64 + wave * 16;
    int nkt = qb + 1;

    bf16x8 qf[4];
#pragma unroll
    for (int st = 0; st < 4; st++)
      qf[st] = *(const bf16x8*)(qbase + (size_t)(qw0 + l15) * rs + st * 32 + quad * 8);

    // prologue DMA: tile 0 of this phase into current buffer
    {
      const bf16* ks = kp;
      const bf16* vs = vp;
#pragma unroll
      for (int i = 0; i < 4; i++) {
        int off = (wave * 4 + i) * 512 + lane * 8;
        async_copy16(ks + off, &Kls[buf][off]);
        async_copy16(vs + off, &Vls[buf][off]);
      }
    }

    f32x4 o[8] = {};
    float mrow[4] = {-INFINITY, -INFINITY, -INFINITY, -INFINITY};
    float lrow[4] = {0.f, 0.f, 0.f, 0.f};

#pragma unroll 1
    for (int kt = 0; kt < nkt; kt++) {
      int k0 = kt * 64;
      int kmax_off = qw0 + 15 - k0;  // wave-uniform
      __syncthreads();  // drains DMA for tile kt; prev-tile readers done

      // Srel band fragments first (in-order vmcnt retire: waiting on these
      // does not drain the prefetch DMA issued below)
      const f16* tb = bnd + (size_t)TRI(qb, kt) * 4096;
      f16x4 srl[4] = {};
#pragma unroll
      for (int nt = 0; nt < 4; nt++)
        if (nt * 16 <= kmax_off)
          srl[nt] = *(const f16x4*)(tb + (wave * 4 + nt) * 256 + l15 * 16 + quad * 4);

      // prefetch DMA: tile kt+1 into alternate buffer
      if (kt + 1 < nkt) {
        const bf16* ks = kp + (size_t)(kt + 1) * (64 * 128);
        const bf16* vs = vp + (size_t)(kt + 1) * (128 * 64);
#pragma unroll
        for (int i = 0; i < 4; i++) {
          int off = (wave * 4 + i) * 512 + lane * 8;
          async_copy16(ks + off, &Kls[buf ^ 1][off]);
          async_copy16(vs + off, &Vls[buf ^ 1][off]);
        }
      }

      // S = Q K^T
      f32x4 sa[4] = {};
#pragma unroll
      for (int nt = 0; nt < 4; nt++) {
        if (nt * 16 <= kmax_off) {
          int kk = nt * 16 + l15;
#pragma unroll
          for (int st = 0; st < 4; st++) {
            bf16x8 kf = *(const bf16x8*)&Kls[buf][kk * 128 + (((st * 4 + quad) ^ l15) & 15) * 8];
            sa[nt] = __builtin_amdgcn_mfma_f32_16x16x32_bf16(qf[st], kf, sa[nt], 0, 0, 0);
          }
        }
      }

      // combine + mask + row max
      float pmx[4] = {-INFINITY, -INFINITY, -INFINITY, -INFINITY};
#pragma unroll
      for (int nt = 0; nt < 4; nt++) {
        if (nt * 16 <= kmax_off) {
          int kg = k0 + nt * 16 + l15;
#pragma unroll
          for (int rg = 0; rg < 4; rg++) {
            int qg = qw0 + quad * 4 + rg;
            float v = (sa[nt][rg] + (float)srl[nt][rg]) * SCALE;
            v = (kg <= qg) ? v : -INFINITY;
            sa[nt][rg] = v;
            pmx[rg] = fmaxf(pmx[rg], v);
          }
        } else {
#pragma unroll
          for (int rg = 0; rg < 4; rg++) sa[nt][rg] = -INFINITY;
        }
      }

      // online softmax (per 16-lane row group)
#pragma unroll
      for (int rg = 0; rg < 4; rg++) {
        float v = pmx[rg];
        v = fmaxf(v, __shfl_xor(v, 1));
        v = fmaxf(v, __shfl_xor(v, 2));
        v = fmaxf(v, __shfl_xor(v, 4));
        v = fmaxf(v, __shfl_xor(v, 8));
        float mnew = fmaxf(mrow[rg], v);
        float alpha = __expf(mrow[rg] - mnew);
        mrow[rg] = mnew;
        lrow[rg] *= alpha;
#pragma unroll
        for (int nt = 0; nt < 8; nt++) o[nt][rg] *= alpha;
        pmx[rg] = mnew;
      }
      float ls[4] = {0.f, 0.f, 0.f, 0.f};
#pragma unroll
      for (int nt = 0; nt < 4; nt++)
#pragma unroll
        for (int rg = 0; rg < 4; rg++) {
          float p = __expf(sa[nt][rg] - pmx[rg]);
          ls[rg] += p;
          Pls[wave][quad * 4 + rg][nt * 16 + l15] = (bf16)p;
        }
#pragma unroll
      for (int rg = 0; rg < 4; rg++) {
        float v = ls[rg];
        v += __shfl_xor(v, 1);
        v += __shfl_xor(v, 2);
        v += __shfl_xor(v, 4);
        v += __shfl_xor(v, 8);
        lrow[rg] += v;
      }
      // Pls is per-wave: same-wave DS ordering suffices, no barrier

      // O += P @ V
      bf16x8 pf[2];
#pragma unroll
      for (int s2 = 0; s2 < 2; s2++)
        pf[s2] = *(const bf16x8*)&Pls[wave][l15][s2 * 32 + quad * 8];
#pragma unroll
      for (int nt = 0; nt < 8; nt++) {
        int d = nt * 16 + l15;
#pragma unroll
        for (int s2 = 0; s2 < 2; s2++) {
          if (s2 * 32 <= kmax_off) {
            bf16x8 vf = *(const bf16x8*)&Vls[buf][d * 64 + (((s2 * 4 + quad) ^ (l15 & 7)) & 7) * 8];
            o[nt] = __builtin_amdgcn_mfma_f32_16x16x32_bf16(pf[s2], vf, o[nt], 0, 0, 0);
          }
        }
      }
      buf ^= 1;
    }

    // finalize phase: O / l -> y[b, q, h*128 + d] bf16
#pragma unroll
    for (int rg = 0; rg < 4; rg++) {
      float inv = 1.0f / lrow[rg];
      int qg = qw0 + quad * 4 + rg;
      bf16* yr = y + ((size_t)b * LL + qg) * DD + h * HSS;
#pragma unroll
      for (int nt = 0; nt < 8; nt++) yr[nt * 16 + l15] = (bf16)(o[nt][rg] * inv);
    }
  }
}

// ---------------------------------------------------------------------------
extern "C" void kernel_launch(void* const* d_in, const int* in_sizes, int n_in,
                              void* d_out, int out_size, void* d_ws, size_t ws_size,
                              hipStream_t stream) {
  const float* x = (const float*)d_in[0];
  const float* W_qkv = (const float*)d_in[1];
  const float* b_qkv = (const float*)d_in[2];
  const float* W_o = (const float*)d_in[3];
  const float* b_o = (const float*)d_in[4];
  const float* Er = (const float*)d_in[5];
  const float* ln1_g = (const float*)d_in[6];
  const float* ln1_b = (const float*)d_in[7];
  const float* ln2_g = (const float*)d_in[8];
  const float* ln2_b = (const float*)d_in[9];
  const float* W_fc = (const float*)d_in[10];
  const float* b_fc = (const float*)d_in[11];
  const float* W_proj = (const float*)d_in[12];
  const float* b_proj = (const float*)d_in[13];
  float* out = (float*)d_out;

  char* p = (char*)d_ws;
  auto alloc = [&](size_t bytes) {
    char* r = p;
    p += (bytes + 255) & ~(size_t)255;
    return r;
  };
  bf16* Wt_qkv = (bf16*)alloc((size_t)3072 * 1024 * 2);
  bf16* Wt_o   = (bf16*)alloc((size_t)1024 * 1024 * 2);
  bf16* Wt_fc  = (bf16*)alloc((size_t)4096 * 1024 * 2);
  bf16* Wt_pr  = (bf16*)alloc((size_t)1024 * 4096 * 2);
  bf16* Erb    = (bf16*)alloc((size_t)1024 * 128 * 2);
  bf16* xn     = (bf16*)alloc((size_t)8192 * 1024 * 2);
  bf16* qkvb   = (bf16*)alloc((size_t)8192 * 3072 * 2);  // + yb = hb region
  bf16* yb     = (bf16*)alloc((size_t)8192 * 1024 * 2);  // must follow qkvb
  bf16* Kpack  = (bf16*)alloc((size_t)64 * 16 * 64 * 128 * 2);
  bf16* Vpack  = (bf16*)alloc((size_t)64 * 16 * 128 * 64 * 2);
  f16*  band   = (f16*)alloc((size_t)64 * 136 * 4096 * 2);  // 71.3 MB
  float* x2    = (float*)band;  // alias: band dead before x2 is written
  bf16* hb     = qkvb;          // spans qkvb+yb (66MB >= 64MB needed)

  // weight prep
  transpose_cast_kernel<<<dim3(3072 / 32, 1024 / 32), dim3(32, 8), 0, stream>>>(W_qkv, Wt_qkv, 1024, 3072);
  transpose_cast_kernel<<<dim3(1024 / 32, 1024 / 32), dim3(32, 8), 0, stream>>>(W_o, Wt_o, 1024, 1024);
  transpose_cast_kernel<<<dim3(4096 / 32, 1024 / 32), dim3(32, 8), 0, stream>>>(W_fc, Wt_fc, 1024, 4096);
  transpose_cast_kernel<<<dim3(1024 / 32, 4096 / 32), dim3(32, 8), 0, stream>>>(W_proj, Wt_pr, 4096, 1024);
  cast_bf16_kernel<<<512, 256, 0, stream>>>(Er, Erb, 1024 * 128);

  // block
  ln_kernel<<<8192, 256, 0, stream>>>(x, ln1_g, ln1_b, xn);
  gemm_kernel<0><<<dim3(24, 64), 256, 0, stream>>>(xn, Wt_qkv, b_qkv, nullptr, qkvb, 8192, 3072, 1024);
  pack_kv_kernel<<<dim3(16, 8, 8), 256, 0, stream>>>(qkvb, Kpack, Vpack);
  relband_kernel<<<dim3(136, 8, 8), 256, 0, stream>>>(qkvb, Erb, band);
  flash_kernel<<<dim3(8, 8, 8), 256, 0, stream>>>(qkvb, Kpack, Vpack, band, yb);
  gemm_kernel<2><<<dim3(8, 64), 256, 0, stream>>>(yb, Wt_o, b_o, x, x2, 8192, 1024, 1024);
  ln_kernel<<<8192, 256, 0, stream>>>(x2, ln2_g, ln2_b, xn);
  gemm_kernel<1><<<dim3(32, 64), 256, 0, stream>>>(xn, Wt_fc, b_fc, nullptr, hb, 8192, 4096, 1024);
  gemm_kernel<2><<<dim3(8, 64), 256, 0, stream>>>(hb, Wt_pr, b_proj, x2, out, 8192, 1024, 4096);
}